// Round 8
// baseline (378.604 us; speedup 1.0000x reference)
//
#include <hip/hip_runtime.h>
#include <stdint.h>

// Problem constants
#define BB    16
#define DIMC  512
#define CHC   256
#define REDC  64
#define LL    32          // H == W == 32
#define NTOK  (BB*LL*LL)  // 16384 tokens

typedef unsigned short u16;
typedef __attribute__((ext_vector_type(4))) float f32x4;
typedef __attribute__((ext_vector_type(8))) short bf16x8;

__device__ __forceinline__ float bf2f(u16 u){
  union { unsigned int i; float f; } v; v.i = ((unsigned int)u) << 16; return v.f;
}
__device__ __forceinline__ u16 f2bf(float f){
  union { float f; unsigned int i; } v; v.f = f;
  unsigned int r = (v.i + 0x7FFFu + ((v.i >> 16) & 1u)) >> 16;
  return (u16)r;
}

// async global->LDS, 16B per lane; LDS base must be wave-uniform.
__device__ __forceinline__ void gload16(const u16* g, u16* l) {
  __builtin_amdgcn_global_load_lds(
      (const __attribute__((address_space(1))) void*)g,
      (__attribute__((address_space(3))) void*)l, 16, 0, 0);
}

// ---------------------------------------------------------------------------
// K0: fused pre-pass. Blocks 0..511: weight transposes fp32 [K][N]->bf16 [N][K].
// Blocks 512..8703: per-(b,ch) axis means -> g[br][b][c][l].
__global__ __launch_bounds__(256) void k_pre(const float* __restrict__ s1,
    u16* __restrict__ d1, const float* __restrict__ s2, u16* __restrict__ d2,
    const float* __restrict__ x, const float* __restrict__ pe_h,
    const float* __restrict__ pe_w, float* __restrict__ g)
{
  int tid = threadIdx.x;
  if (blockIdx.x < 512) {
    __shared__ u16 t[64][65];
    int bid = blockIdx.x;
    const float* src; u16* dst; int K, N, n0, k0;
    if (bid < 256) { src = s1; dst = d1; K = 512;  N = 2048; n0 = (bid & 31) * 64; k0 = (bid >> 5) * 64; }
    else { bid -= 256; src = s2; dst = d2; K = 2048; N = 512; n0 = (bid & 7) * 64; k0 = (bid >> 3) * 64; }
    #pragma unroll
    for (int i = 0; i < 16; ++i) {
      int idx = i*256 + tid; int r = idx >> 6, c = idx & 63;
      t[r][c] = f2bf(src[(size_t)(k0 + r) * N + n0 + c]);
    }
    __syncthreads();
    #pragma unroll
    for (int i = 0; i < 16; ++i) {
      int idx = i*256 + tid; int c = idx >> 6, r = idx & 63;
      dst[(size_t)(n0 + c) * K + k0 + r] = t[r][c];
    }
    return;
  }
  // ---- means part ----
  int bc = blockIdx.x - 512;           // b*512 + ch
  int br = (bc & 511) >> 8, c = bc & 255;
  __shared__ float tt[32][33];
  const float* xp = x + (size_t)bc * 1024;
  float4 v = ((const float4*)xp)[tid];
  int h = tid >> 3, w4 = (tid & 7) * 4;
  tt[h][w4+0] = v.x; tt[h][w4+1] = v.y; tt[h][w4+2] = v.z; tt[h][w4+3] = v.w;
  __syncthreads();
  if (tid < 32) {
    float rs = 0.f;
    if (br == 0) {
      #pragma unroll
      for (int w = 0; w < 32; ++w) rs += tt[tid][w];     // mean over W (H-branch)
    } else {
      #pragma unroll
      for (int h2 = 0; h2 < 32; ++h2) rs += tt[h2][tid]; // mean over H (W-branch)
    }
    float tot = rs;
    #pragma unroll
    for (int off = 16; off >= 1; off >>= 1) tot += __shfl_xor(tot, off);
    const float* pe = (br == 0 ? pe_h : pe_w) + c*32;
    float pv = pe[tid];
    float pm = pv;
    #pragma unroll
    for (int off = 16; off >= 1; off >>= 1) pm += __shfl_xor(pm, off);
    int b = bc >> 9;
    float gv = rs * (1.f/32.f) + tot * (1.f/1024.f) + pv + pm * (1.f/32.f);
    g[((size_t)(br*BB + b)*256 + c)*32 + tid] = gv;
  }
}

// ---------------------------------------------------------------------------
// K2: generator net: conv1(256->64,k3) -> BN -> hardswish -> conv2(64->256,k3)
//     -> per-batch filter norm * fns + fnm.  One block per (branch, batch).
__global__ __launch_bounds__(256) void k_gen(
    const float* __restrict__ g, float* __restrict__ wout,
    const float* g1w_h, const float* bng_h, const float* bnb_h, const float* bnrm_h,
    const float* bnrv_h, const float* g2w_h, const float* fns_h, const float* fnm_h,
    const float* g1w_w, const float* bng_w, const float* bnb_w, const float* bnrm_w,
    const float* bnrv_w, const float* g2w_w, const float* fns_w, const float* fnm_w)
{
  int br = blockIdx.x >> 4, b = blockIdx.x & 15;
  const float* g1w  = br ? g1w_w  : g1w_h;
  const float* bng  = br ? bng_w  : bng_h;
  const float* bnb  = br ? bnb_w  : bnb_h;
  const float* bnrm = br ? bnrm_w : bnrm_h;
  const float* bnrv = br ? bnrv_w : bnrv_h;
  const float* g2w  = br ? g2w_w  : g2w_h;
  const float* fns  = br ? fns_w  : fns_h;
  const float* fnm  = br ? fnm_w  : fnm_h;

  __shared__ float gs[256][34];   // padded: col 0 and 33 are zero
  __shared__ float h1[64][34];
  __shared__ float red[8];
  int tid = threadIdx.x;
  const float* gb = g + (size_t)(br*BB + b) * 8192;

  gs[tid][0] = 0.f; gs[tid][33] = 0.f;
  if (tid < 64) { h1[tid][0] = 0.f; h1[tid][33] = 0.f; }
  #pragma unroll
  for (int it = 0; it < 32; ++it) {
    int idx = it*256 + tid;
    gs[idx >> 5][1 + (idx & 31)] = gb[idx];
  }
  __syncthreads();

  // conv1: thread -> (r = tid>>2, 8 l-values)
  {
    int r = tid >> 2, l0 = (tid & 3) * 8;
    float acc[8];
    #pragma unroll
    for (int j = 0; j < 8; ++j) acc[j] = 0.f;
    for (int c = 0; c < 256; ++c) {
      const float* wp = g1w + (r*256 + c)*3;
      float w0 = wp[0], w1 = wp[1], w2 = wp[2];
      float gv[10];
      #pragma unroll
      for (int q = 0; q < 10; ++q) gv[q] = gs[c][l0 + q];
      #pragma unroll
      for (int j = 0; j < 8; ++j) acc[j] += w0*gv[j] + w1*gv[j+1] + w2*gv[j+2];
    }
    float sc = bng[r] * rsqrtf(bnrv[r] + 1e-5f);
    float sh = bnb[r] - bnrm[r] * sc;
    #pragma unroll
    for (int j = 0; j < 8; ++j) {
      float v2 = acc[j]*sc + sh;                                    // BN
      float hs = v2 * fminf(fmaxf(v2 + 3.f, 0.f), 6.f) * (1.f/6.f); // hardswish
      h1[r][1 + l0 + j] = hs;
    }
  }
  __syncthreads();

  // conv2: thread -> one output channel c, all 32 l
  int c = tid;
  float a2[32];
  #pragma unroll
  for (int l = 0; l < 32; ++l) a2[l] = 0.f;
  for (int r = 0; r < 64; ++r) {
    const float* wp = g2w + (c*64 + r)*3;
    float w0 = wp[0], w1 = wp[1], w2 = wp[2];
    float hv[34];
    #pragma unroll
    for (int q = 0; q < 34; ++q) hv[q] = h1[r][q];
    #pragma unroll
    for (int l = 0; l < 32; ++l) a2[l] += w0*hv[l] + w1*hv[l+1] + w2*hv[l+2];
  }
  // per-batch mean/var over all (c,l)
  float s = 0.f, sq = 0.f;
  #pragma unroll
  for (int l = 0; l < 32; ++l) { s += a2[l]; sq += a2[l]*a2[l]; }
  #pragma unroll
  for (int off = 32; off >= 1; off >>= 1) { s += __shfl_xor(s, off); sq += __shfl_xor(sq, off); }
  int wid = tid >> 6;
  if ((tid & 63) == 0) { red[wid*2] = s; red[wid*2+1] = sq; }
  __syncthreads();
  float S  = red[0] + red[2] + red[4] + red[6];
  float SQ = red[1] + red[3] + red[5] + red[7];
  float u   = S * (1.f/8192.f);
  float var = SQ * (1.f/8192.f) - u*u;
  float inv = rsqrtf(var + 1e-6f);
  float* wo = wout + (size_t)(br*BB + b)*8192 + c*32;
  #pragma unroll
  for (int l = 0; l < 32; ++l)
    wo[l] = (a2[l] - u)*inv*fns[c*32 + l] + fnm[c*32 + l];
}

// ---------------------------------------------------------------------------
// K3: circulant apply per (b,ch). Writes ybr bf16 in (b,ch,h,w) layout.
__global__ __launch_bounds__(256) void k_circ(const float* __restrict__ x,
    const float* __restrict__ pe_h, const float* __restrict__ pe_w,
    const float* __restrict__ bias_h, const float* __restrict__ bias_w,
    const float* __restrict__ wgt, u16* __restrict__ ybr)
{
  int bc = blockIdx.x;
  int b = bc >> 9, ch = bc & 511, br = ch >> 8, c = ch & 255;
  __shared__ float xs[32][33];
  __shared__ float ww[32];
  int tid = threadIdx.x;
  const float* xp = x + (size_t)bc * 1024;
  float4 v = ((const float4*)xp)[tid];
  int h = tid >> 3, w4 = (tid & 7) * 4;
  if (br == 0) {
    float p = pe_h[c*32 + h];
    xs[h][w4+0] = v.x + p; xs[h][w4+1] = v.y + p;
    xs[h][w4+2] = v.z + p; xs[h][w4+3] = v.w + p;
  } else {
    xs[h][w4+0] = v.x + pe_w[c*32 + w4+0];
    xs[h][w4+1] = v.y + pe_w[c*32 + w4+1];
    xs[h][w4+2] = v.z + pe_w[c*32 + w4+2];
    xs[h][w4+3] = v.w + pe_w[c*32 + w4+3];
  }
  if (tid < 32) ww[tid] = wgt[((size_t)(br*BB + b)*256 + c)*32 + tid];
  __syncthreads();
  float bias = (br ? bias_w : bias_h)[c];
  int i = tid >> 3;
  float o0 = bias, o1 = bias, o2 = bias, o3 = bias;
  if (br == 0) {
    #pragma unroll
    for (int k = 0; k < 32; ++k) {
      float wk = ww[k]; int rr = (i + k) & 31;
      o0 += wk*xs[rr][w4+0]; o1 += wk*xs[rr][w4+1];
      o2 += wk*xs[rr][w4+2]; o3 += wk*xs[rr][w4+3];
    }
  } else {
    #pragma unroll
    for (int k = 0; k < 32; ++k) {
      float wk = ww[k];
      o0 += wk*xs[i][(w4+0+k) & 31]; o1 += wk*xs[i][(w4+1+k) & 31];
      o2 += wk*xs[i][(w4+2+k) & 31]; o3 += wk*xs[i][(w4+3+k) & 31];
    }
  }
  ushort4 o; o.x = f2bf(o0); o.y = f2bf(o1); o.z = f2bf(o2); o.w = f2bf(o3);
  ((ushort4*)(ybr + (size_t)bc * 1024))[tid] = o;
}

// ---------------------------------------------------------------------------
// K4: transpose (b,ch,h,w)->token-major + LayerNorm over 512 channels.
__global__ __launch_bounds__(256) void k_ln(const u16* __restrict__ ybr,
    const float* __restrict__ ln_w, const float* __restrict__ ln_b,
    u16* __restrict__ A)
{
  int bh = blockIdx.x; int b = bh >> 5, h = bh & 31;
  __shared__ float ys[512][33];
  __shared__ float ps[8][32], pq[8][32];
  __shared__ float mus[32], rstds[32];
  __shared__ float lw[512], lb[512];
  int tid = threadIdx.x;
  lw[tid]       = ln_w[tid];       lb[tid]       = ln_b[tid];
  lw[tid + 256] = ln_w[tid + 256]; lb[tid + 256] = ln_b[tid + 256];
  #pragma unroll
  for (int it = 0; it < 16; ++it) {
    int vid = it*256 + tid; int ch = vid >> 3; int w4 = (vid & 7) * 4;
    ushort4 v = *(const ushort4*)(ybr + (size_t)(b*512 + ch)*1024 + h*32 + w4);
    ys[ch][w4+0] = bf2f(v.x); ys[ch][w4+1] = bf2f(v.y);
    ys[ch][w4+2] = bf2f(v.z); ys[ch][w4+3] = bf2f(v.w);
  }
  __syncthreads();
  int w = tid & 31, gq = tid >> 5;
  float s = 0.f, sq = 0.f;
  for (int cc = gq*64; cc < gq*64 + 64; ++cc) { float vv = ys[cc][w]; s += vv; sq += vv*vv; }
  ps[gq][w] = s; pq[gq][w] = sq;
  __syncthreads();
  if (tid < 32) {
    float S = 0.f, SQ = 0.f;
    #pragma unroll
    for (int q = 0; q < 8; ++q) { S += ps[q][tid]; SQ += pq[q][tid]; }
    float mu = S * (1.f/512.f);
    float var = SQ * (1.f/512.f) - mu*mu;
    mus[tid] = mu; rstds[tid] = rsqrtf(var + 1e-6f);
  }
  __syncthreads();
  u16* Arow = A + (size_t)(b*1024 + h*32) * 512;
  #pragma unroll
  for (int it = 0; it < 64; ++it) {
    int idx = it*256 + tid; int w2 = idx >> 9, cc = idx & 511;
    float val = (ys[cc][w2] - mus[w2]) * rstds[w2] * lw[cc] + lb[cc];
    Arow[(size_t)w2*512 + cc] = f2bf(val);
  }
}

// ---------------------------------------------------------------------------
// K5/K6: MFMA GEMM, 128x128 tile, BK=64, 8 waves / 512 threads, 16x16x32 bf16.
// A: LDS double-buffer (A-only, 32 KB total), gload_lds staging with the
//    verified XOR chunk involution (0 bank conflicts).
// B: fragments loaded DIRECTLY from global (B1/B2 = 2 MB, L2-resident) --
//    halves LDS-pipe traffic, which round-7 arithmetic showed was binding
//    (96 KB/block/K-tile over a 256 B/clk pipe > matrix-pipe time).
// vmcnt choreography (in-order counting): per iter issue 8 B loads (tile t),
// sched_barrier, stage A(t+1) [2 gload_lds], vmcnt(10) -> drains exactly the
// 2 oldest (A(t)); compiler auto-waits vmcnt(2) before B use, keeping A(t+1)
// in flight. Last iter: vmcnt(8).
// EPI=1: Z = gelu_approx(A@B + bias) bf16. EPI=2: residual fp32 out.
template<int EPI>
__global__ __launch_bounds__(512, 4) void k_gemm(
    const u16* __restrict__ A, const u16* __restrict__ BT,
    void* __restrict__ outv, const float* __restrict__ xin,
    const float* __restrict__ bias, const float* __restrict__ gamma,
    int K, int N, int a_row_off, int out_row_off)
{
  __shared__ u16 As[2][8192];
  int tid = threadIdx.x;
  int m0 = blockIdx.x * 128, n0 = blockIdx.y * 128;
  int lane = tid & 63, wid = tid >> 6;
  int wr = wid >> 1, wc = wid & 1;          // wave tile: rows wr*32.., cols wc*64..
  f32x4 acc[2][4];
  #pragma unroll
  for (int mi = 0; mi < 2; ++mi)
    #pragma unroll
    for (int ni = 0; ni < 4; ++ni) acc[mi][ni] = (f32x4){0.f,0.f,0.f,0.f};

  // A staging: 1024 chunks of 16B per tile. LDS chunk q (linear) holds
  // logical (row = q>>3, colchunk = (q&7) ^ ((q>>3)&7)).
  const u16* Ag[2]; int cbs[2];
  #pragma unroll
  for (int i = 0; i < 2; ++i) {
    int cb = wid*128 + i*64;            // wave-uniform chunk base
    int q  = cb + lane;
    int r  = q >> 3, ccs = (q & 7) ^ (r & 7);   // pre-swizzled source chunk
    Ag[i] = A + (size_t)(a_row_off + m0 + r)*K + ccs*8;
    cbs[i] = cb*8;                      // u16 index of wave-uniform LDS base
  }
  // B fragment base: row n0 + wc*64 + (lane&15), k-chunk (lane>>4)
  const u16* bRow = BT + (size_t)(n0 + wc*64 + (lane & 15))*K + (lane >> 4)*8;

  auto stageA = [&](int t, int slot) {
    int k0 = t << 6;
    #pragma unroll
    for (int i = 0; i < 2; ++i) gload16(Ag[i] + k0, &As[slot][cbs[i]]);
  };

  int nt = K >> 6;
  stageA(0, 0);                         // prologue

  for (int t = 0; t < nt; ++t) {
    int cur = t & 1;
    int k0 = t << 6;
    // B fragments for tile t straight from global/L2 (no barrier dependency)
    bf16x8 bfr[4][2];
    #pragma unroll
    for (int ni = 0; ni < 4; ++ni)
      #pragma unroll
      for (int kx = 0; kx < 2; ++kx)
        bfr[ni][kx] = *(const bf16x8*)(bRow + (size_t)ni*16*K + kx*32 + k0);
    __builtin_amdgcn_sched_barrier(0);  // keep B loads before the A stage
    if (t + 1 < nt) {
      stageA(t + 1, cur ^ 1);
      asm volatile("s_waitcnt vmcnt(10)" ::: "memory");  // drain A(t) only
    } else {
      asm volatile("s_waitcnt vmcnt(8)" ::: "memory");   // drain A(t); B in flight
    }
    __builtin_amdgcn_s_barrier();                        // tile t collectively valid
    const u16* Ar = &As[cur][0];
    #pragma unroll
    for (int kk = 0; kk < 64; kk += 32) {
      bf16x8 af[2];
      #pragma unroll
      for (int mi = 0; mi < 2; ++mi) {
        int row = wr*32 + mi*16 + (lane & 15);
        int j = (kk >> 3) + (lane >> 4);            // logical colchunk 0..7
        af[mi] = *(const bf16x8*)&Ar[row*64 + ((j ^ (row & 7)) << 3)];
      }
      int kx = kk >> 5;
      #pragma unroll
      for (int mi = 0; mi < 2; ++mi)
        #pragma unroll
        for (int ni = 0; ni < 4; ++ni)
          acc[mi][ni] = __builtin_amdgcn_mfma_f32_16x16x32_bf16(af[mi], bfr[ni][kx], acc[mi][ni], 0, 0, 0);
    }
    __builtin_amdgcn_s_barrier();   // protect the slot the next stage overwrites
  }

  // epilogue: D layout col = lane&15, row = (lane>>4)*4 + reg
  #pragma unroll
  for (int mi = 0; mi < 2; ++mi) {
    #pragma unroll
    for (int ni = 0; ni < 4; ++ni) {
      int n = n0 + wc*64 + ni*16 + (lane & 15);
      float bn = bias[n];
      #pragma unroll
      for (int r = 0; r < 4; ++r) {
        int m = m0 + wr*32 + mi*16 + (lane >> 4)*4 + r;
        float v = acc[mi][ni][r] + bn;
        if (EPI == 1) {
          float ge = v / (1.f + __expf(-1.702f * v));   // sigmoid-approx GELU
          ((u16*)outv)[(size_t)m*N + n] = f2bf(ge);
        } else {
          float yv = gamma[n] * v;
          int mg = out_row_off + m;
          int bb = mg >> 10, hh = (mg >> 5) & 31, wv = mg & 31;
          size_t oi = ((size_t)(bb*512 + n))*1024 + hh*32 + wv;
          ((float*)outv)[oi] = xin[oi] + yv;
        }
      }
    }
  }
}

// ---------------------------------------------------------------------------
extern "C" void kernel_launch(void* const* d_in, const int* in_sizes, int n_in,
                              void* d_out, int out_size, void* d_ws, size_t ws_size,
                              hipStream_t stream)
{
  const float* x      = (const float*)d_in[0];
  const float* pe_h   = (const float*)d_in[1];
  const float* g1w_h  = (const float*)d_in[2];
  const float* bng_h  = (const float*)d_in[3];
  const float* bnb_h  = (const float*)d_in[4];
  const float* bnrm_h = (const float*)d_in[5];
  const float* bnrv_h = (const float*)d_in[6];
  const float* g2w_h  = (const float*)d_in[7];
  const float* fns_h  = (const float*)d_in[8];
  const float* fnm_h  = (const float*)d_in[9];
  const float* bias_h = (const float*)d_in[10];
  const float* pe_w   = (const float*)d_in[11];
  const float* g1w_w  = (const float*)d_in[12];
  const float* bng_w  = (const float*)d_in[13];
  const float* bnb_w  = (const float*)d_in[14];
  const float* bnrm_w = (const float*)d_in[15];
  const float* bnrv_w = (const float*)d_in[16];
  const float* g2w_w  = (const float*)d_in[17];
  const float* fns_w  = (const float*)d_in[18];
  const float* fnm_w  = (const float*)d_in[19];
  const float* bias_w = (const float*)d_in[20];
  const float* ln_w   = (const float*)d_in[21];
  const float* ln_b   = (const float*)d_in[22];
  const float* pw1w   = (const float*)d_in[23];
  const float* pw1b   = (const float*)d_in[24];
  const float* pw2w   = (const float*)d_in[25];
  const float* pw2b   = (const float*)d_in[26];
  const float* gamma  = (const float*)d_in[27];
  float* out = (float*)d_out;

  char* ws = (char*)d_ws;
  size_t off = 0;
  auto carve = [&](size_t bytes) -> void* {
    void* p = ws + off; off += (bytes + 255) & ~(size_t)255; return p;
  };
  float* g   = (float*)carve((size_t)2*BB*256*32*4);   // 1 MB
  float* wgt = (float*)carve((size_t)2*BB*256*32*4);   // 1 MB
  u16* BT1   = (u16*)carve((size_t)2048*512*2);        // 2 MB
  u16* BT2   = (u16*)carve((size_t)512*2048*2);        // 2 MB
  u16* Abuf  = (u16*)carve((size_t)NTOK*512*2);        // 16.8 MB
  size_t tail = off;                                   // ybr / Z share this region
  u16* ybr = (u16*)(ws + tail);
  u16* Z   = (u16*)(ws + tail);                        // Z overwrites dead ybr
  size_t ybr_bytes = (size_t)NTOK*512*2;               // 16.8 MB
  int nch = 1;                                         // chunk M so Z fits in ws
  while (nch < 16) {
    size_t zb = ((size_t)NTOK/nch)*2048*2;
    size_t need = tail + (zb > ybr_bytes ? zb : ybr_bytes);
    if (need <= ws_size) break;
    nch *= 2;
  }

  k_pre<<<512 + BB*512, 256, 0, stream>>>(pw1w, BT1, pw2w, BT2, x, pe_h, pe_w, g);
  k_gen<<<32, 256, 0, stream>>>(g, wgt,
      g1w_h, bng_h, bnb_h, bnrm_h, bnrv_h, g2w_h, fns_h, fnm_h,
      g1w_w, bng_w, bnb_w, bnrm_w, bnrv_w, g2w_w, fns_w, fnm_w);
  k_circ<<<BB*512, 256, 0, stream>>>(x, pe_h, pe_w, bias_h, bias_w, wgt, ybr);
  k_ln<<<BB*LL, 256, 0, stream>>>(ybr, ln_w, ln_b, Abuf);

  int Mc = NTOK / nch;
  for (int ci = 0; ci < nch; ++ci) {
    int moff = ci * Mc;
    k_gemm<1><<<dim3(Mc/128, 2048/128), 512, 0, stream>>>(
        Abuf, BT1, Z, nullptr, pw1b, nullptr, 512, 2048, moff, 0);
    k_gemm<2><<<dim3(Mc/128, 512/128), 512, 0, stream>>>(
        Z, BT2, out, x, pw2b, gamma, 2048, 512, 0, moff);
  }
}

// Round 9
// 218.978 us; speedup vs baseline: 1.7290x; 1.7290x over previous
//
#include <hip/hip_runtime.h>
#include <stdint.h>

// Problem constants
#define BB    16
#define DIMC  512
#define CHC   256
#define REDC  64
#define LL    32          // H == W == 32
#define NTOK  (BB*LL*LL)  // 16384 tokens

typedef unsigned short u16;
typedef __attribute__((ext_vector_type(4))) float f32x4;
typedef __attribute__((ext_vector_type(8))) short bf16x8;

__device__ __forceinline__ float bf2f(u16 u){
  union { unsigned int i; float f; } v; v.i = ((unsigned int)u) << 16; return v.f;
}
__device__ __forceinline__ u16 f2bf(float f){
  union { float f; unsigned int i; } v; v.f = f;
  unsigned int r = (v.i + 0x7FFFu + ((v.i >> 16) & 1u)) >> 16;
  return (u16)r;
}

// async global->LDS, 16B per lane; LDS base must be wave-uniform.
__device__ __forceinline__ void gload16(const u16* g, u16* l) {
  __builtin_amdgcn_global_load_lds(
      (const __attribute__((address_space(1))) void*)g,
      (__attribute__((address_space(3))) void*)l, 16, 0, 0);
}

// ---------------------------------------------------------------------------
// K0: fused pre-pass. Blocks 0..511: weight transposes fp32 [K][N]->bf16 [N][K].
// Blocks 512..8703: per-(b,ch) axis means -> g[br][b][c][l].
__global__ __launch_bounds__(256) void k_pre(const float* __restrict__ s1,
    u16* __restrict__ d1, const float* __restrict__ s2, u16* __restrict__ d2,
    const float* __restrict__ x, const float* __restrict__ pe_h,
    const float* __restrict__ pe_w, float* __restrict__ g)
{
  int tid = threadIdx.x;
  if (blockIdx.x < 512) {
    __shared__ u16 t[64][65];
    int bid = blockIdx.x;
    const float* src; u16* dst; int K, N, n0, k0;
    if (bid < 256) { src = s1; dst = d1; K = 512;  N = 2048; n0 = (bid & 31) * 64; k0 = (bid >> 5) * 64; }
    else { bid -= 256; src = s2; dst = d2; K = 2048; N = 512; n0 = (bid & 7) * 64; k0 = (bid >> 3) * 64; }
    #pragma unroll
    for (int i = 0; i < 16; ++i) {
      int idx = i*256 + tid; int r = idx >> 6, c = idx & 63;
      t[r][c] = f2bf(src[(size_t)(k0 + r) * N + n0 + c]);
    }
    __syncthreads();
    #pragma unroll
    for (int i = 0; i < 16; ++i) {
      int idx = i*256 + tid; int c = idx >> 6, r = idx & 63;
      dst[(size_t)(n0 + c) * K + k0 + r] = t[r][c];
    }
    return;
  }
  // ---- means part ----
  int bc = blockIdx.x - 512;           // b*512 + ch
  int br = (bc & 511) >> 8, c = bc & 255;
  __shared__ float tt[32][33];
  const float* xp = x + (size_t)bc * 1024;
  float4 v = ((const float4*)xp)[tid];
  int h = tid >> 3, w4 = (tid & 7) * 4;
  tt[h][w4+0] = v.x; tt[h][w4+1] = v.y; tt[h][w4+2] = v.z; tt[h][w4+3] = v.w;
  __syncthreads();
  if (tid < 32) {
    float rs = 0.f;
    if (br == 0) {
      #pragma unroll
      for (int w = 0; w < 32; ++w) rs += tt[tid][w];     // mean over W (H-branch)
    } else {
      #pragma unroll
      for (int h2 = 0; h2 < 32; ++h2) rs += tt[h2][tid]; // mean over H (W-branch)
    }
    float tot = rs;
    #pragma unroll
    for (int off = 16; off >= 1; off >>= 1) tot += __shfl_xor(tot, off);
    const float* pe = (br == 0 ? pe_h : pe_w) + c*32;
    float pv = pe[tid];
    float pm = pv;
    #pragma unroll
    for (int off = 16; off >= 1; off >>= 1) pm += __shfl_xor(pm, off);
    int b = bc >> 9;
    float gv = rs * (1.f/32.f) + tot * (1.f/1024.f) + pv + pm * (1.f/32.f);
    g[((size_t)(br*BB + b)*256 + c)*32 + tid] = gv;
  }
}

// ---------------------------------------------------------------------------
// K2: generator net: conv1(256->64,k3) -> BN -> hardswish -> conv2(64->256,k3)
//     -> per-batch filter norm * fns + fnm.  One block per (branch, batch).
__global__ __launch_bounds__(256) void k_gen(
    const float* __restrict__ g, float* __restrict__ wout,
    const float* g1w_h, const float* bng_h, const float* bnb_h, const float* bnrm_h,
    const float* bnrv_h, const float* g2w_h, const float* fns_h, const float* fnm_h,
    const float* g1w_w, const float* bng_w, const float* bnb_w, const float* bnrm_w,
    const float* bnrv_w, const float* g2w_w, const float* fns_w, const float* fnm_w)
{
  int br = blockIdx.x >> 4, b = blockIdx.x & 15;
  const float* g1w  = br ? g1w_w  : g1w_h;
  const float* bng  = br ? bng_w  : bng_h;
  const float* bnb  = br ? bnb_w  : bnb_h;
  const float* bnrm = br ? bnrm_w : bnrm_h;
  const float* bnrv = br ? bnrv_w : bnrv_h;
  const float* g2w  = br ? g2w_w  : g2w_h;
  const float* fns  = br ? fns_w  : fns_h;
  const float* fnm  = br ? fnm_w  : fnm_h;

  __shared__ float gs[256][34];   // padded: col 0 and 33 are zero
  __shared__ float h1[64][34];
  __shared__ float red[8];
  int tid = threadIdx.x;
  const float* gb = g + (size_t)(br*BB + b) * 8192;

  gs[tid][0] = 0.f; gs[tid][33] = 0.f;
  if (tid < 64) { h1[tid][0] = 0.f; h1[tid][33] = 0.f; }
  #pragma unroll
  for (int it = 0; it < 32; ++it) {
    int idx = it*256 + tid;
    gs[idx >> 5][1 + (idx & 31)] = gb[idx];
  }
  __syncthreads();

  // conv1: thread -> (r = tid>>2, 8 l-values)
  {
    int r = tid >> 2, l0 = (tid & 3) * 8;
    float acc[8];
    #pragma unroll
    for (int j = 0; j < 8; ++j) acc[j] = 0.f;
    for (int c = 0; c < 256; ++c) {
      const float* wp = g1w + (r*256 + c)*3;
      float w0 = wp[0], w1 = wp[1], w2 = wp[2];
      float gv[10];
      #pragma unroll
      for (int q = 0; q < 10; ++q) gv[q] = gs[c][l0 + q];
      #pragma unroll
      for (int j = 0; j < 8; ++j) acc[j] += w0*gv[j] + w1*gv[j+1] + w2*gv[j+2];
    }
    float sc = bng[r] * rsqrtf(bnrv[r] + 1e-5f);
    float sh = bnb[r] - bnrm[r] * sc;
    #pragma unroll
    for (int j = 0; j < 8; ++j) {
      float v2 = acc[j]*sc + sh;                                    // BN
      float hs = v2 * fminf(fmaxf(v2 + 3.f, 0.f), 6.f) * (1.f/6.f); // hardswish
      h1[r][1 + l0 + j] = hs;
    }
  }
  __syncthreads();

  // conv2: thread -> one output channel c, all 32 l
  int c = tid;
  float a2[32];
  #pragma unroll
  for (int l = 0; l < 32; ++l) a2[l] = 0.f;
  for (int r = 0; r < 64; ++r) {
    const float* wp = g2w + (c*64 + r)*3;
    float w0 = wp[0], w1 = wp[1], w2 = wp[2];
    float hv[34];
    #pragma unroll
    for (int q = 0; q < 34; ++q) hv[q] = h1[r][q];
    #pragma unroll
    for (int l = 0; l < 32; ++l) a2[l] += w0*hv[l] + w1*hv[l+1] + w2*hv[l+2];
  }
  // per-batch mean/var over all (c,l)
  float s = 0.f, sq = 0.f;
  #pragma unroll
  for (int l = 0; l < 32; ++l) { s += a2[l]; sq += a2[l]*a2[l]; }
  #pragma unroll
  for (int off = 32; off >= 1; off >>= 1) { s += __shfl_xor(s, off); sq += __shfl_xor(sq, off); }
  int wid = tid >> 6;
  if ((tid & 63) == 0) { red[wid*2] = s; red[wid*2+1] = sq; }
  __syncthreads();
  float S  = red[0] + red[2] + red[4] + red[6];
  float SQ = red[1] + red[3] + red[5] + red[7];
  float u   = S * (1.f/8192.f);
  float var = SQ * (1.f/8192.f) - u*u;
  float inv = rsqrtf(var + 1e-6f);
  float* wo = wout + (size_t)(br*BB + b)*8192 + c*32;
  #pragma unroll
  for (int l = 0; l < 32; ++l)
    wo[l] = (a2[l] - u)*inv*fns[c*32 + l] + fnm[c*32 + l];
}

// ---------------------------------------------------------------------------
// K3: circulant apply per (b,ch). Writes ybr bf16 in (b,ch,h,w) layout.
__global__ __launch_bounds__(256) void k_circ(const float* __restrict__ x,
    const float* __restrict__ pe_h, const float* __restrict__ pe_w,
    const float* __restrict__ bias_h, const float* __restrict__ bias_w,
    const float* __restrict__ wgt, u16* __restrict__ ybr)
{
  int bc = blockIdx.x;
  int b = bc >> 9, ch = bc & 511, br = ch >> 8, c = ch & 255;
  __shared__ float xs[32][33];
  __shared__ float ww[32];
  int tid = threadIdx.x;
  const float* xp = x + (size_t)bc * 1024;
  float4 v = ((const float4*)xp)[tid];
  int h = tid >> 3, w4 = (tid & 7) * 4;
  if (br == 0) {
    float p = pe_h[c*32 + h];
    xs[h][w4+0] = v.x + p; xs[h][w4+1] = v.y + p;
    xs[h][w4+2] = v.z + p; xs[h][w4+3] = v.w + p;
  } else {
    xs[h][w4+0] = v.x + pe_w[c*32 + w4+0];
    xs[h][w4+1] = v.y + pe_w[c*32 + w4+1];
    xs[h][w4+2] = v.z + pe_w[c*32 + w4+2];
    xs[h][w4+3] = v.w + pe_w[c*32 + w4+3];
  }
  if (tid < 32) ww[tid] = wgt[((size_t)(br*BB + b)*256 + c)*32 + tid];
  __syncthreads();
  float bias = (br ? bias_w : bias_h)[c];
  int i = tid >> 3;
  float o0 = bias, o1 = bias, o2 = bias, o3 = bias;
  if (br == 0) {
    #pragma unroll
    for (int k = 0; k < 32; ++k) {
      float wk = ww[k]; int rr = (i + k) & 31;
      o0 += wk*xs[rr][w4+0]; o1 += wk*xs[rr][w4+1];
      o2 += wk*xs[rr][w4+2]; o3 += wk*xs[rr][w4+3];
    }
  } else {
    #pragma unroll
    for (int k = 0; k < 32; ++k) {
      float wk = ww[k];
      o0 += wk*xs[i][(w4+0+k) & 31]; o1 += wk*xs[i][(w4+1+k) & 31];
      o2 += wk*xs[i][(w4+2+k) & 31]; o3 += wk*xs[i][(w4+3+k) & 31];
    }
  }
  ushort4 o; o.x = f2bf(o0); o.y = f2bf(o1); o.z = f2bf(o2); o.w = f2bf(o3);
  ((ushort4*)(ybr + (size_t)bc * 1024))[tid] = o;
}

// ---------------------------------------------------------------------------
// K4: transpose (b,ch,h,w)->token-major + LayerNorm over 512 channels.
__global__ __launch_bounds__(256) void k_ln(const u16* __restrict__ ybr,
    const float* __restrict__ ln_w, const float* __restrict__ ln_b,
    u16* __restrict__ A)
{
  int bh = blockIdx.x; int b = bh >> 5, h = bh & 31;
  __shared__ float ys[512][33];
  __shared__ float ps[8][32], pq[8][32];
  __shared__ float mus[32], rstds[32];
  __shared__ float lw[512], lb[512];
  int tid = threadIdx.x;
  lw[tid]       = ln_w[tid];       lb[tid]       = ln_b[tid];
  lw[tid + 256] = ln_w[tid + 256]; lb[tid + 256] = ln_b[tid + 256];
  #pragma unroll
  for (int it = 0; it < 16; ++it) {
    int vid = it*256 + tid; int ch = vid >> 3; int w4 = (vid & 7) * 4;
    ushort4 v = *(const ushort4*)(ybr + (size_t)(b*512 + ch)*1024 + h*32 + w4);
    ys[ch][w4+0] = bf2f(v.x); ys[ch][w4+1] = bf2f(v.y);
    ys[ch][w4+2] = bf2f(v.z); ys[ch][w4+3] = bf2f(v.w);
  }
  __syncthreads();
  int w = tid & 31, gq = tid >> 5;
  float s = 0.f, sq = 0.f;
  for (int cc = gq*64; cc < gq*64 + 64; ++cc) { float vv = ys[cc][w]; s += vv; sq += vv*vv; }
  ps[gq][w] = s; pq[gq][w] = sq;
  __syncthreads();
  if (tid < 32) {
    float S = 0.f, SQ = 0.f;
    #pragma unroll
    for (int q = 0; q < 8; ++q) { S += ps[q][tid]; SQ += pq[q][tid]; }
    float mu = S * (1.f/512.f);
    float var = SQ * (1.f/512.f) - mu*mu;
    mus[tid] = mu; rstds[tid] = rsqrtf(var + 1e-6f);
  }
  __syncthreads();
  u16* Arow = A + (size_t)(b*1024 + h*32) * 512;
  #pragma unroll
  for (int it = 0; it < 64; ++it) {
    int idx = it*256 + tid; int w2 = idx >> 9, cc = idx & 511;
    float val = (ys[cc][w2] - mus[w2]) * rstds[w2] * lw[cc] + lb[cc];
    Arow[(size_t)w2*512 + cc] = f2bf(val);
  }
}

// ---------------------------------------------------------------------------
// K5/K6: 8-phase (4 phases/K-tile) counted-vmcnt MFMA GEMM. BM=256, BK=64,
// 512 threads / 8 waves (2M x 4N), per-wave 128 x (BN/4). 16x16x32 bf16.
// Per K-tile t (buffer b=t&1):
//  ph0: read B frags (into VGPR, whole K-tile) + A stripe0; stage A-s3(t+1)->b^1;
//       barrier; lgkmcnt0; setprio; 16 MFMA; barrier
//  ph1: read A stripe1; stage B(t+2)+A-s0(t+2)->b; barrier; ... MFMA; barrier
//  ph2: read A stripe2; stage A-s1(t+2);   ...
//  ph3: read A stripe3; stage A-s2(t+2); MFMA; vmcnt(STEADY or 0); barrier
// Stage targets are provably dead since the previous phase's closing barrier.
// vmcnt ledger (per wave, in-order): steady-state newest = B(t+2)xBUNITS +
// A-s0..2(t+2) = BUNITS+3 units -> vmcnt(BUNITS+3) confirms tile t+1 fully
// landed while keeping a full K-tile (~4 phases of MFMA) in flight.
// LDS: linear gload_lds dest + XOR chunk involution (c^(row&7)) on BOTH
// global source and ds_read addresses (verified 0 bank conflicts, r4-r7).
// EPI=1: Z = gelu_approx(A@B + bias) bf16. EPI=2: residual fp32 out.
template<int BN, int EPI>
__global__ __launch_bounds__(512, 2) void k_gemm8(
    const u16* __restrict__ A, const u16* __restrict__ BT,
    void* __restrict__ outv, const float* __restrict__ xin,
    const float* __restrict__ bias, const float* __restrict__ gamma,
    int K, int N, int a_row_off, int out_row_off)
{
  constexpr int NREP   = BN / 64;       // B frags per wave
  constexpr int WN     = BN / 4;        // per-wave N extent
  constexpr int BUNITS = BN / 64;       // 8KB stage units per B K-tile
  __shared__ u16 As[2][256*64];
  __shared__ u16 Bs[2][BN*64];
  int tid = threadIdx.x;
  int lane = tid & 63, wid = tid >> 6;
  int wr = wid >> 2, wc = wid & 3;
  int m0 = blockIdx.x * 256, n0 = blockIdx.y * BN;

  f32x4 acc[8][NREP];
  #pragma unroll
  for (int mi = 0; mi < 8; ++mi)
    #pragma unroll
    for (int ni = 0; ni < NREP; ++ni) acc[mi][ni] = (f32x4){0.f,0.f,0.f,0.f};

  // ---- stage helpers (each = 1 vmcnt unit per wave per call item) ----
  // A stripe p of tile tt: rows {32p..32p+32} u {128+32p..+32} (dead after ph p)
  auto stageA = [&](int tt, int p, int b) {
    int rg = (wid < 4) ? (p*32 + wid*8) : (128 + p*32 + (wid - 4)*8);
    int row = rg + (lane >> 3);
    int c = (lane & 7) ^ (row & 7);
    gload16(A + (size_t)(a_row_off + m0 + row)*K + tt*64 + c*8, &As[b][rg*64]);
  };
  auto stageB = [&](int tt, int b) {
    #pragma unroll
    for (int u = 0; u < BUNITS; ++u) {
      int rg = u*64 + wid*8;
      int row = rg + (lane >> 3);
      int c = (lane & 7) ^ (row & 7);
      gload16(BT + (size_t)(n0 + row)*K + tt*64 + c*8, &Bs[b][rg*64]);
    }
  };
  auto readA = [&](int p, int b, bf16x8 (&af)[2][2]) {
    #pragma unroll
    for (int i = 0; i < 2; ++i) {
      int row = wr*128 + (2*p + i)*16 + (lane & 15);
      #pragma unroll
      for (int kx = 0; kx < 2; ++kx) {
        int j = kx*4 + (lane >> 4);
        af[i][kx] = *(const bf16x8*)&As[b][row*64 + ((j ^ (row & 7)) << 3)];
      }
    }
  };

  int nt = K >> 6;    // >= 8 for both GEMMs
  // ---- prologue: tile0 fully + tile1 minus its s3 ----
  stageB(0, 0);
  stageA(0, 0, 0); stageA(0, 1, 0); stageA(0, 2, 0);
  stageA(0, 3, 0);
  stageB(1, 1);
  stageA(1, 0, 1); stageA(1, 1, 1); stageA(1, 2, 1);
  if constexpr (BUNITS == 4) asm volatile("s_waitcnt vmcnt(7)" ::: "memory");
  else                       asm volatile("s_waitcnt vmcnt(5)" ::: "memory");
  __builtin_amdgcn_s_barrier();

  for (int t = 0; t < nt; ++t) {
    int b = t & 1;
    bool m1 = (t + 1 < nt), m2 = (t + 2 < nt);
    bf16x8 bfr[NREP][2], af[2][2];

    // -------- phase 0 --------
    #pragma unroll
    for (int ni = 0; ni < NREP; ++ni) {
      int row = wc*WN + ni*16 + (lane & 15);
      #pragma unroll
      for (int kx = 0; kx < 2; ++kx) {
        int j = kx*4 + (lane >> 4);
        bfr[ni][kx] = *(const bf16x8*)&Bs[b][row*64 + ((j ^ (row & 7)) << 3)];
      }
    }
    readA(0, b, af);
    if (m1) stageA(t + 1, 3, b ^ 1);
    __builtin_amdgcn_s_barrier();
    asm volatile("s_waitcnt lgkmcnt(0)" ::: "memory");
    __builtin_amdgcn_sched_barrier(0);
    __builtin_amdgcn_s_setprio(1);
    #pragma unroll
    for (int i = 0; i < 2; ++i)
      #pragma unroll
      for (int kx = 0; kx < 2; ++kx)
        #pragma unroll
        for (int ni = 0; ni < NREP; ++ni)
          acc[i][ni] = __builtin_amdgcn_mfma_f32_16x16x32_bf16(af[i][kx], bfr[ni][kx], acc[i][ni], 0, 0, 0);
    __builtin_amdgcn_s_setprio(0);
    __builtin_amdgcn_s_barrier();

    // -------- phases 1..3 --------
    #pragma unroll
    for (int p = 1; p < 4; ++p) {
      readA(p, b, af);
      if (p == 1) { if (m2) { stageB(t + 2, b); stageA(t + 2, 0, b); } }
      else        { if (m2) stageA(t + 2, p - 1, b); }
      __builtin_amdgcn_s_barrier();
      asm volatile("s_waitcnt lgkmcnt(0)" ::: "memory");
      __builtin_amdgcn_sched_barrier(0);
      __builtin_amdgcn_s_setprio(1);
      #pragma unroll
      for (int i = 0; i < 2; ++i)
        #pragma unroll
        for (int kx = 0; kx < 2; ++kx)
          #pragma unroll
          for (int ni = 0; ni < NREP; ++ni)
            acc[2*p + i][ni] = __builtin_amdgcn_mfma_f32_16x16x32_bf16(af[i][kx], bfr[ni][kx], acc[2*p + i][ni], 0, 0, 0);
      __builtin_amdgcn_s_setprio(0);
      if (p == 3) {
        if (m2) {
          if constexpr (BUNITS == 4) asm volatile("s_waitcnt vmcnt(7)" ::: "memory");
          else                       asm volatile("s_waitcnt vmcnt(5)" ::: "memory");
        } else {
          asm volatile("s_waitcnt vmcnt(0)" ::: "memory");
        }
      }
      __builtin_amdgcn_s_barrier();
    }
  }

  // epilogue: D layout col = lane&15, row = (lane>>4)*4 + reg
  #pragma unroll
  for (int mi = 0; mi < 8; ++mi) {
    #pragma unroll
    for (int ni = 0; ni < NREP; ++ni) {
      int n = n0 + wc*WN + ni*16 + (lane & 15);
      float bn = bias[n];
      #pragma unroll
      for (int r = 0; r < 4; ++r) {
        int m = m0 + wr*128 + mi*16 + (lane >> 4)*4 + r;
        float v = acc[mi][ni][r] + bn;
        if (EPI == 1) {
          float ge = v / (1.f + __expf(-1.702f * v));   // sigmoid-approx GELU
          ((u16*)outv)[(size_t)m*N + n] = f2bf(ge);
        } else {
          float yv = gamma[n] * v;
          int mg = out_row_off + m;
          int bb = mg >> 10, hh = (mg >> 5) & 31, wv = mg & 31;
          size_t oi = ((size_t)(bb*512 + n))*1024 + hh*32 + wv;
          ((float*)outv)[oi] = xin[oi] + yv;
        }
      }
    }
  }
}

// ---------------------------------------------------------------------------
extern "C" void kernel_launch(void* const* d_in, const int* in_sizes, int n_in,
                              void* d_out, int out_size, void* d_ws, size_t ws_size,
                              hipStream_t stream)
{
  const float* x      = (const float*)d_in[0];
  const float* pe_h   = (const float*)d_in[1];
  const float* g1w_h  = (const float*)d_in[2];
  const float* bng_h  = (const float*)d_in[3];
  const float* bnb_h  = (const float*)d_in[4];
  const float* bnrm_h = (const float*)d_in[5];
  const float* bnrv_h = (const float*)d_in[6];
  const float* g2w_h  = (const float*)d_in[7];
  const float* fns_h  = (const float*)d_in[8];
  const float* fnm_h  = (const float*)d_in[9];
  const float* bias_h = (const float*)d_in[10];
  const float* pe_w   = (const float*)d_in[11];
  const float* g1w_w  = (const float*)d_in[12];
  const float* bng_w  = (const float*)d_in[13];
  const float* bnb_w  = (const float*)d_in[14];
  const float* bnrm_w = (const float*)d_in[15];
  const float* bnrv_w = (const float*)d_in[16];
  const float* g2w_w  = (const float*)d_in[17];
  const float* fns_w  = (const float*)d_in[18];
  const float* fnm_w  = (const float*)d_in[19];
  const float* bias_w = (const float*)d_in[20];
  const float* ln_w   = (const float*)d_in[21];
  const float* ln_b   = (const float*)d_in[22];
  const float* pw1w   = (const float*)d_in[23];
  const float* pw1b   = (const float*)d_in[24];
  const float* pw2w   = (const float*)d_in[25];
  const float* pw2b   = (const float*)d_in[26];
  const float* gamma  = (const float*)d_in[27];
  float* out = (float*)d_out;

  char* ws = (char*)d_ws;
  size_t off = 0;
  auto carve = [&](size_t bytes) -> void* {
    void* p = ws + off; off += (bytes + 255) & ~(size_t)255; return p;
  };
  float* g   = (float*)carve((size_t)2*BB*256*32*4);   // 1 MB
  float* wgt = (float*)carve((size_t)2*BB*256*32*4);   // 1 MB
  u16* BT1   = (u16*)carve((size_t)2048*512*2);        // 2 MB
  u16* BT2   = (u16*)carve((size_t)512*2048*2);        // 2 MB
  u16* Abuf  = (u16*)carve((size_t)NTOK*512*2);        // 16.8 MB
  size_t tail = off;                                   // ybr / Z share this region
  u16* ybr = (u16*)(ws + tail);
  u16* Z   = (u16*)(ws + tail);                        // Z overwrites dead ybr
  size_t ybr_bytes = (size_t)NTOK*512*2;               // 16.8 MB
  int nch = 1;                                         // chunk M so Z fits in ws
  while (nch < 16) {
    size_t zb = ((size_t)NTOK/nch)*2048*2;
    size_t need = tail + (zb > ybr_bytes ? zb : ybr_bytes);
    if (need <= ws_size) break;
    nch *= 2;
  }

  k_pre<<<512 + BB*512, 256, 0, stream>>>(pw1w, BT1, pw2w, BT2, x, pe_h, pe_w, g);
  k_gen<<<32, 256, 0, stream>>>(g, wgt,
      g1w_h, bng_h, bnb_h, bnrm_h, bnrv_h, g2w_h, fns_h, fnm_h,
      g1w_w, bng_w, bnb_w, bnrm_w, bnrv_w, g2w_w, fns_w, fnm_w);
  k_circ<<<BB*512, 256, 0, stream>>>(x, pe_h, pe_w, bias_h, bias_w, wgt, ybr);
  k_ln<<<BB*LL, 256, 0, stream>>>(ybr, ln_w, ln_b, Abuf);

  int Mc = NTOK / nch;
  for (int ci = 0; ci < nch; ++ci) {
    int moff = ci * Mc;
    k_gemm8<256,1><<<dim3(Mc/256, 2048/256), 512, 0, stream>>>(
        Abuf, BT1, Z, nullptr, pw1b, nullptr, 512, 2048, moff, 0);
    k_gemm8<128,2><<<dim3(Mc/256, 512/128), 512, 0, stream>>>(
        Z, BT2, out, x, pw2b, gamma, 2048, 512, 0, moff);
  }
}

// Round 10
// 188.180 us; speedup vs baseline: 2.0119x; 1.1637x over previous
//
#include <hip/hip_runtime.h>
#include <stdint.h>

// Problem constants
#define BB    16
#define DIMC  512
#define CHC   256
#define REDC  64
#define LL    32          // H == W == 32
#define NTOK  (BB*LL*LL)  // 16384 tokens

typedef unsigned short u16;
typedef unsigned char  u8;
typedef __attribute__((ext_vector_type(4))) float f32x4;

__device__ __forceinline__ float bf2f(u16 u){
  union { unsigned int i; float f; } v; v.i = ((unsigned int)u) << 16; return v.f;
}
__device__ __forceinline__ u16 f2bf(float f){
  union { float f; unsigned int i; } v; v.f = f;
  unsigned int r = (v.i + 0x7FFFu + ((v.i >> 16) & 1u)) >> 16;
  return (u16)r;
}
__device__ __forceinline__ unsigned int pk4_fp8(float a, float b, float c, float d){
  unsigned int w = 0;
  w = __builtin_amdgcn_cvt_pk_fp8_f32(a, b, w, false);
  w = __builtin_amdgcn_cvt_pk_fp8_f32(c, d, w, true);
  return w;
}
__device__ __forceinline__ u8 f2fp8(float f){
  return (u8)(__builtin_amdgcn_cvt_pk_fp8_f32(f, f, 0, false) & 0xffu);
}

// async global->LDS, 16B per lane; LDS base must be wave-uniform.
__device__ __forceinline__ void gload16(const u8* g, u8* l) {
  __builtin_amdgcn_global_load_lds(
      (const __attribute__((address_space(1))) void*)g,
      (__attribute__((address_space(3))) void*)l, 16, 0, 0);
}

// ---------------------------------------------------------------------------
// K0: fused pre-pass. Blocks 0..511: weight transpose fp32 [K][N] -> fp8 [N][K].
// Blocks 512..8703: per-(b,ch) axis means -> g[br][b][c][l].
__global__ __launch_bounds__(256) void k_pre(const float* __restrict__ s1,
    u8* __restrict__ d1, const float* __restrict__ s2, u8* __restrict__ d2,
    const float* __restrict__ x, const float* __restrict__ pe_h,
    const float* __restrict__ pe_w, float* __restrict__ g)
{
  int tid = threadIdx.x;
  if (blockIdx.x < 512) {
    __shared__ float tf[64][65];
    int bid = blockIdx.x;
    const float* src; u8* dst; int K, N, n0, k0;
    if (bid < 256) { src = s1; dst = d1; K = 512;  N = 2048; n0 = (bid & 31) * 64; k0 = (bid >> 5) * 64; }
    else { bid -= 256; src = s2; dst = d2; K = 2048; N = 512; n0 = (bid & 7) * 64; k0 = (bid >> 3) * 64; }
    #pragma unroll
    for (int i = 0; i < 16; ++i) {
      int idx = i*256 + tid; int r = idx >> 6, c = idx & 63;
      tf[r][c] = src[(size_t)(k0 + r) * N + n0 + c];
    }
    __syncthreads();
    // writer: thread -> (c = tid>>2, 16-byte k-group gq = tid&3)
    int c = tid >> 2, gq = tid & 3;
    uint4 o;
    unsigned int* op = (unsigned int*)&o;
    #pragma unroll
    for (int d = 0; d < 4; ++d) {
      int j = gq*16 + d*4;
      op[d] = pk4_fp8(tf[j+0][c], tf[j+1][c], tf[j+2][c], tf[j+3][c]);
    }
    *(uint4*)(dst + (size_t)(n0 + c)*K + k0 + gq*16) = o;
    return;
  }
  // ---- means part ----
  int bc = blockIdx.x - 512;           // b*512 + ch
  int br = (bc & 511) >> 8, c = bc & 255;
  __shared__ float tt[32][33];
  const float* xp = x + (size_t)bc * 1024;
  float4 v = ((const float4*)xp)[tid];
  int h = tid >> 3, w4 = (tid & 7) * 4;
  tt[h][w4+0] = v.x; tt[h][w4+1] = v.y; tt[h][w4+2] = v.z; tt[h][w4+3] = v.w;
  __syncthreads();
  if (tid < 32) {
    float rs = 0.f;
    if (br == 0) {
      #pragma unroll
      for (int w = 0; w < 32; ++w) rs += tt[tid][w];     // mean over W (H-branch)
    } else {
      #pragma unroll
      for (int h2 = 0; h2 < 32; ++h2) rs += tt[h2][tid]; // mean over H (W-branch)
    }
    float tot = rs;
    #pragma unroll
    for (int off = 16; off >= 1; off >>= 1) tot += __shfl_xor(tot, off);
    const float* pe = (br == 0 ? pe_h : pe_w) + c*32;
    float pv = pe[tid];
    float pm = pv;
    #pragma unroll
    for (int off = 16; off >= 1; off >>= 1) pm += __shfl_xor(pm, off);
    int b = bc >> 9;
    float gv = rs * (1.f/32.f) + tot * (1.f/1024.f) + pv + pm * (1.f/32.f);
    g[((size_t)(br*BB + b)*256 + c)*32 + tid] = gv;
  }
}

// ---------------------------------------------------------------------------
// K2: generator net: conv1(256->64,k3) -> BN -> hardswish -> conv2(64->256,k3)
//     -> per-batch filter norm * fns + fnm.  One block per (branch, batch).
__global__ __launch_bounds__(256) void k_gen(
    const float* __restrict__ g, float* __restrict__ wout,
    const float* g1w_h, const float* bng_h, const float* bnb_h, const float* bnrm_h,
    const float* bnrv_h, const float* g2w_h, const float* fns_h, const float* fnm_h,
    const float* g1w_w, const float* bng_w, const float* bnb_w, const float* bnrm_w,
    const float* bnrv_w, const float* g2w_w, const float* fns_w, const float* fnm_w)
{
  int br = blockIdx.x >> 4, b = blockIdx.x & 15;
  const float* g1w  = br ? g1w_w  : g1w_h;
  const float* bng  = br ? bng_w  : bng_h;
  const float* bnb  = br ? bnb_w  : bnb_h;
  const float* bnrm = br ? bnrm_w : bnrm_h;
  const float* bnrv = br ? bnrv_w : bnrv_h;
  const float* g2w  = br ? g2w_w  : g2w_h;
  const float* fns  = br ? fns_w  : fns_h;
  const float* fnm  = br ? fnm_w  : fnm_h;

  __shared__ float gs[256][34];   // padded: col 0 and 33 are zero
  __shared__ float h1[64][34];
  __shared__ float red[8];
  int tid = threadIdx.x;
  const float* gb = g + (size_t)(br*BB + b) * 8192;

  gs[tid][0] = 0.f; gs[tid][33] = 0.f;
  if (tid < 64) { h1[tid][0] = 0.f; h1[tid][33] = 0.f; }
  #pragma unroll
  for (int it = 0; it < 32; ++it) {
    int idx = it*256 + tid;
    gs[idx >> 5][1 + (idx & 31)] = gb[idx];
  }
  __syncthreads();

  // conv1: thread -> (r = tid>>2, 8 l-values)
  {
    int r = tid >> 2, l0 = (tid & 3) * 8;
    float acc[8];
    #pragma unroll
    for (int j = 0; j < 8; ++j) acc[j] = 0.f;
    for (int c = 0; c < 256; ++c) {
      const float* wp = g1w + (r*256 + c)*3;
      float w0 = wp[0], w1 = wp[1], w2 = wp[2];
      float gv[10];
      #pragma unroll
      for (int q = 0; q < 10; ++q) gv[q] = gs[c][l0 + q];
      #pragma unroll
      for (int j = 0; j < 8; ++j) acc[j] += w0*gv[j] + w1*gv[j+1] + w2*gv[j+2];
    }
    float sc = bng[r] * rsqrtf(bnrv[r] + 1e-5f);
    float sh = bnb[r] - bnrm[r] * sc;
    #pragma unroll
    for (int j = 0; j < 8; ++j) {
      float v2 = acc[j]*sc + sh;                                    // BN
      float hs = v2 * fminf(fmaxf(v2 + 3.f, 0.f), 6.f) * (1.f/6.f); // hardswish
      h1[r][1 + l0 + j] = hs;
    }
  }
  __syncthreads();

  // conv2: thread -> one output channel c, all 32 l
  int c = tid;
  float a2[32];
  #pragma unroll
  for (int l = 0; l < 32; ++l) a2[l] = 0.f;
  for (int r = 0; r < 64; ++r) {
    const float* wp = g2w + (c*64 + r)*3;
    float w0 = wp[0], w1 = wp[1], w2 = wp[2];
    float hv[34];
    #pragma unroll
    for (int q = 0; q < 34; ++q) hv[q] = h1[r][q];
    #pragma unroll
    for (int l = 0; l < 32; ++l) a2[l] += w0*hv[l] + w1*hv[l+1] + w2*hv[l+2];
  }
  // per-batch mean/var over all (c,l)
  float s = 0.f, sq = 0.f;
  #pragma unroll
  for (int l = 0; l < 32; ++l) { s += a2[l]; sq += a2[l]*a2[l]; }
  #pragma unroll
  for (int off = 32; off >= 1; off >>= 1) { s += __shfl_xor(s, off); sq += __shfl_xor(sq, off); }
  int wid = tid >> 6;
  if ((tid & 63) == 0) { red[wid*2] = s; red[wid*2+1] = sq; }
  __syncthreads();
  float S  = red[0] + red[2] + red[4] + red[6];
  float SQ = red[1] + red[3] + red[5] + red[7];
  float u   = S * (1.f/8192.f);
  float var = SQ * (1.f/8192.f) - u*u;
  float inv = rsqrtf(var + 1e-6f);
  float* wo = wout + (size_t)(br*BB + b)*8192 + c*32;
  #pragma unroll
  for (int l = 0; l < 32; ++l)
    wo[l] = (a2[l] - u)*inv*fns[c*32 + l] + fnm[c*32 + l];
}

// ---------------------------------------------------------------------------
// K3: circulant apply per (b,ch). Writes ybr bf16 in (b,ch,h,w) layout.
__global__ __launch_bounds__(256) void k_circ(const float* __restrict__ x,
    const float* __restrict__ pe_h, const float* __restrict__ pe_w,
    const float* __restrict__ bias_h, const float* __restrict__ bias_w,
    const float* __restrict__ wgt, u16* __restrict__ ybr)
{
  int bc = blockIdx.x;
  int b = bc >> 9, ch = bc & 511, br = ch >> 8, c = ch & 255;
  __shared__ float xs[32][33];
  __shared__ float ww[32];
  int tid = threadIdx.x;
  const float* xp = x + (size_t)bc * 1024;
  float4 v = ((const float4*)xp)[tid];
  int h = tid >> 3, w4 = (tid & 7) * 4;
  if (br == 0) {
    float p = pe_h[c*32 + h];
    xs[h][w4+0] = v.x + p; xs[h][w4+1] = v.y + p;
    xs[h][w4+2] = v.z + p; xs[h][w4+3] = v.w + p;
  } else {
    xs[h][w4+0] = v.x + pe_w[c*32 + w4+0];
    xs[h][w4+1] = v.y + pe_w[c*32 + w4+1];
    xs[h][w4+2] = v.z + pe_w[c*32 + w4+2];
    xs[h][w4+3] = v.w + pe_w[c*32 + w4+3];
  }
  if (tid < 32) ww[tid] = wgt[((size_t)(br*BB + b)*256 + c)*32 + tid];
  __syncthreads();
  float bias = (br ? bias_w : bias_h)[c];
  int i = tid >> 3;
  float o0 = bias, o1 = bias, o2 = bias, o3 = bias;
  if (br == 0) {
    #pragma unroll
    for (int k = 0; k < 32; ++k) {
      float wk = ww[k]; int rr = (i + k) & 31;
      o0 += wk*xs[rr][w4+0]; o1 += wk*xs[rr][w4+1];
      o2 += wk*xs[rr][w4+2]; o3 += wk*xs[rr][w4+3];
    }
  } else {
    #pragma unroll
    for (int k = 0; k < 32; ++k) {
      float wk = ww[k];
      o0 += wk*xs[i][(w4+0+k) & 31]; o1 += wk*xs[i][(w4+1+k) & 31];
      o2 += wk*xs[i][(w4+2+k) & 31]; o3 += wk*xs[i][(w4+3+k) & 31];
    }
  }
  ushort4 o; o.x = f2bf(o0); o.y = f2bf(o1); o.z = f2bf(o2); o.w = f2bf(o3);
  ((ushort4*)(ybr + (size_t)bc * 1024))[tid] = o;
}

// ---------------------------------------------------------------------------
// K4: transpose (b,ch,h,w)->token-major + LayerNorm + fp8 pack. A8 [token][512].
__global__ __launch_bounds__(256) void k_ln(const u16* __restrict__ ybr,
    const float* __restrict__ ln_w, const float* __restrict__ ln_b,
    u8* __restrict__ A8)
{
  int bh = blockIdx.x; int b = bh >> 5, h = bh & 31;
  __shared__ float ys[512][33];
  __shared__ float ps[8][32], pq[8][32];
  __shared__ float mus[32], rstds[32];
  __shared__ float lw[512], lb[512];
  int tid = threadIdx.x;
  lw[tid]       = ln_w[tid];       lb[tid]       = ln_b[tid];
  lw[tid + 256] = ln_w[tid + 256]; lb[tid + 256] = ln_b[tid + 256];
  #pragma unroll
  for (int it = 0; it < 16; ++it) {
    int vid = it*256 + tid; int ch = vid >> 3; int w4 = (vid & 7) * 4;
    ushort4 v = *(const ushort4*)(ybr + (size_t)(b*512 + ch)*1024 + h*32 + w4);
    ys[ch][w4+0] = bf2f(v.x); ys[ch][w4+1] = bf2f(v.y);
    ys[ch][w4+2] = bf2f(v.z); ys[ch][w4+3] = bf2f(v.w);
  }
  __syncthreads();
  int w = tid & 31, gq = tid >> 5;
  float s = 0.f, sq = 0.f;
  for (int cc = gq*64; cc < gq*64 + 64; ++cc) { float vv = ys[cc][w]; s += vv; sq += vv*vv; }
  ps[gq][w] = s; pq[gq][w] = sq;
  __syncthreads();
  if (tid < 32) {
    float S = 0.f, SQ = 0.f;
    #pragma unroll
    for (int q = 0; q < 8; ++q) { S += ps[q][tid]; SQ += pq[q][tid]; }
    float mu = S * (1.f/512.f);
    float var = SQ * (1.f/512.f) - mu*mu;
    mus[tid] = mu; rstds[tid] = rsqrtf(var + 1e-6f);
  }
  __syncthreads();
  u8* Arow = A8 + (size_t)(b*1024 + h*32) * 512;
  #pragma unroll
  for (int it = 0; it < 16; ++it) {
    int idx = it*256 + tid;                 // 4096 dword groups
    int w2 = idx >> 7, cg = idx & 127; int cc = cg*4;
    float mu = mus[w2], rs2 = rstds[w2];
    float v0 = (ys[cc+0][w2] - mu) * rs2 * lw[cc+0] + lb[cc+0];
    float v1 = (ys[cc+1][w2] - mu) * rs2 * lw[cc+1] + lb[cc+1];
    float v2 = (ys[cc+2][w2] - mu) * rs2 * lw[cc+2] + lb[cc+2];
    float v3 = (ys[cc+3][w2] - mu) * rs2 * lw[cc+3] + lb[cc+3];
    ((unsigned int*)(Arow + (size_t)w2*512))[cg] = pk4_fp8(v0, v1, v2, v3);
  }
}

// ---------------------------------------------------------------------------
// K5/K6: fp8 MFMA GEMM, 128x128 tile, BK=64 (bytes), 8 waves / 512 threads,
// mfma_f32_16x16x32_fp8_fp8 (same lane mapping as the validated bf16 case;
// frag = 8 fp8 = one b64 LDS read -> LDS-pipe cycles HALVED vs bf16, which
// the R7 cycle audit showed was the binding resource).
// Pipeline: R7-proven 2-slot dbuf, stage(t+1) -> counted vmcnt(2) -> raw
// s_barrier -> ds_read+MFMA -> raw s_barrier. 1 A + 1 B gload16 per wave.
// Swizzle: 16B chunk c of 64B row r stored at c ^ ((r>>1)&3) (involution on
// BOTH global source and read addr); b64 frag reads land 2-way on banks=free.
// EPI=1: Z = fp8(gelu_approx(A@B + bias)). EPI=2: residual fp32 out.
template<int EPI>
__global__ __launch_bounds__(512, 4) void k_gemm(
    const u8* __restrict__ A, const u8* __restrict__ BT,
    void* __restrict__ outv, const float* __restrict__ xin,
    const float* __restrict__ bias, const float* __restrict__ gamma,
    int K, int N, int a_row_off, int out_row_off)
{
  __shared__ u8 As[2][8192];
  __shared__ u8 Bs[2][8192];
  int tid = threadIdx.x;
  int m0 = blockIdx.x * 128, n0 = blockIdx.y * 128;
  int lane = tid & 63, wid = tid >> 6;
  int wr = wid >> 1, wc = wid & 1;          // wave tile: rows wr*32.., cols wc*64..
  f32x4 acc[2][4];
  #pragma unroll
  for (int mi = 0; mi < 2; ++mi)
    #pragma unroll
    for (int ni = 0; ni < 4; ++ni) acc[mi][ni] = (f32x4){0.f,0.f,0.f,0.f};

  // staging: tile = 128 rows x 64 B; unit (=wave) u covers rows 16u..16u+15.
  // lane l -> row 16u + (l>>2), 16B chunk (l&3); source chunk XOR-swizzled.
  int rloc = (wid << 4) + (lane >> 2);
  int cp   = (lane & 3) ^ ((lane >> 3) & 3);
  const u8* aSrc = A  + (size_t)(a_row_off + m0 + rloc)*K + cp*16;
  const u8* bSrc = BT + (size_t)(n0 + rloc)*K + cp*16;
  int ldsOff = wid * 1024;                  // wave-uniform byte base

  auto stage = [&](int t, int slot) {
    int k0 = t << 6;
    gload16(aSrc + k0, &As[slot][ldsOff]);
    gload16(bSrc + k0, &Bs[slot][ldsOff]);
  };
  // b64 fragment read: global bytes [row][kk + q*8 .. +8]
  auto lds8 = [&](const u8* base, int row, int kk, int q) -> long {
    int j = (kk >> 4) + (q >> 1);
    int byte = row*64 + ((j ^ ((row >> 1) & 3)) << 4) + ((q & 1) << 3);
    return *(const long*)(base + byte);
  };

  int nt = K >> 6;
  stage(0, 0);                              // prologue

  for (int t = 0; t < nt; ++t) {
    int cur = t & 1;
    if (t + 1 < nt) {
      stage(t + 1, cur ^ 1);
      asm volatile("s_waitcnt vmcnt(2)" ::: "memory");   // tile-t loads landed
    } else {
      asm volatile("s_waitcnt vmcnt(0)" ::: "memory");
    }
    __builtin_amdgcn_s_barrier();                        // tile t collectively valid
    const u8* Ar = &As[cur][0];
    const u8* Br = &Bs[cur][0];
    int q = lane >> 4;
    #pragma unroll
    for (int kk = 0; kk < 64; kk += 32) {
      long af[2], bfr[4];
      #pragma unroll
      for (int mi = 0; mi < 2; ++mi)
        af[mi] = lds8(Ar, wr*32 + mi*16 + (lane & 15), kk, q);
      #pragma unroll
      for (int ni = 0; ni < 4; ++ni)
        bfr[ni] = lds8(Br, wc*64 + ni*16 + (lane & 15), kk, q);
      #pragma unroll
      for (int mi = 0; mi < 2; ++mi)
        #pragma unroll
        for (int ni = 0; ni < 4; ++ni)
          acc[mi][ni] = __builtin_amdgcn_mfma_f32_16x16x32_fp8_fp8(af[mi], bfr[ni], acc[mi][ni], 0, 0, 0);
    }
    __builtin_amdgcn_s_barrier();   // protect the slot the next stage overwrites
  }

  // epilogue: D layout col = lane&15, row = (lane>>4)*4 + reg
  #pragma unroll
  for (int mi = 0; mi < 2; ++mi) {
    #pragma unroll
    for (int ni = 0; ni < 4; ++ni) {
      int n = n0 + wc*64 + ni*16 + (lane & 15);
      float bn = bias[n];
      #pragma unroll
      for (int r = 0; r < 4; ++r) {
        int m = m0 + wr*32 + mi*16 + (lane >> 4)*4 + r;
        float v = acc[mi][ni][r] + bn;
        if (EPI == 1) {
          float ge = v / (1.f + __expf(-1.702f * v));   // sigmoid-approx GELU
          ((u8*)outv)[(size_t)m*N + n] = f2fp8(ge);
        } else {
          float yv = gamma[n] * v;
          int mg = out_row_off + m;
          int bb = mg >> 10, hh = (mg >> 5) & 31, wv = mg & 31;
          size_t oi = ((size_t)(bb*512 + n))*1024 + hh*32 + wv;
          ((float*)outv)[oi] = xin[oi] + yv;
        }
      }
    }
  }
}

// ---------------------------------------------------------------------------
extern "C" void kernel_launch(void* const* d_in, const int* in_sizes, int n_in,
                              void* d_out, int out_size, void* d_ws, size_t ws_size,
                              hipStream_t stream)
{
  const float* x      = (const float*)d_in[0];
  const float* pe_h   = (const float*)d_in[1];
  const float* g1w_h  = (const float*)d_in[2];
  const float* bng_h  = (const float*)d_in[3];
  const float* bnb_h  = (const float*)d_in[4];
  const float* bnrm_h = (const float*)d_in[5];
  const float* bnrv_h = (const float*)d_in[6];
  const float* g2w_h  = (const float*)d_in[7];
  const float* fns_h  = (const float*)d_in[8];
  const float* fnm_h  = (const float*)d_in[9];
  const float* bias_h = (const float*)d_in[10];
  const float* pe_w   = (const float*)d_in[11];
  const float* g1w_w  = (const float*)d_in[12];
  const float* bng_w  = (const float*)d_in[13];
  const float* bnb_w  = (const float*)d_in[14];
  const float* bnrm_w = (const float*)d_in[15];
  const float* bnrv_w = (const float*)d_in[16];
  const float* g2w_w  = (const float*)d_in[17];
  const float* fns_w  = (const float*)d_in[18];
  const float* fnm_w  = (const float*)d_in[19];
  const float* bias_w = (const float*)d_in[20];
  const float* ln_w   = (const float*)d_in[21];
  const float* ln_b   = (const float*)d_in[22];
  const float* pw1w   = (const float*)d_in[23];
  const float* pw1b   = (const float*)d_in[24];
  const float* pw2w   = (const float*)d_in[25];
  const float* pw2b   = (const float*)d_in[26];
  const float* gamma  = (const float*)d_in[27];
  float* out = (float*)d_out;

  char* ws = (char*)d_ws;
  size_t off = 0;
  auto carve = [&](size_t bytes) -> void* {
    void* p = ws + off; off += (bytes + 255) & ~(size_t)255; return p;
  };
  float* g   = (float*)carve((size_t)2*BB*256*32*4);   // 1 MB
  float* wgt = (float*)carve((size_t)2*BB*256*32*4);   // 1 MB
  u8* BT1    = (u8*)carve((size_t)2048*512);           // 1 MB fp8
  u8* BT2    = (u8*)carve((size_t)512*2048);           // 1 MB fp8
  u8* Abuf   = (u8*)carve((size_t)NTOK*512);           // 8.4 MB fp8
  size_t tail = off;                                   // ybr / Z share this region
  u16* ybr = (u16*)(ws + tail);
  u8*  Z   = (u8*)(ws + tail);                         // Z overwrites dead ybr
  size_t ybr_bytes = (size_t)NTOK*512*2;               // 16.8 MB
  int nch = 1;                                         // chunk M so Z fits in ws
  while (nch < 16) {
    size_t zb = ((size_t)NTOK/nch)*2048;               // fp8 Z
    size_t need = tail + (zb > ybr_bytes ? zb : ybr_bytes);
    if (need <= ws_size) break;
    nch *= 2;
  }

  k_pre<<<512 + BB*512, 256, 0, stream>>>(pw1w, BT1, pw2w, BT2, x, pe_h, pe_w, g);
  k_gen<<<32, 256, 0, stream>>>(g, wgt,
      g1w_h, bng_h, bnb_h, bnrm_h, bnrv_h, g2w_h, fns_h, fnm_h,
      g1w_w, bng_w, bnb_w, bnrm_w, bnrv_w, g2w_w, fns_w, fnm_w);
  k_circ<<<BB*512, 256, 0, stream>>>(x, pe_h, pe_w, bias_h, bias_w, wgt, ybr);
  k_ln<<<BB*LL, 256, 0, stream>>>(ybr, ln_w, ln_b, Abuf);

  int Mc = NTOK / nch;
  for (int ci = 0; ci < nch; ++ci) {
    int moff = ci * Mc;
    k_gemm<1><<<dim3(Mc/128, 2048/128), 512, 0, stream>>>(
        Abuf, BT1, Z, nullptr, pw1b, nullptr, 512, 2048, moff, 0);
    k_gemm<2><<<dim3(Mc/128, 512/128), 512, 0, stream>>>(
        Z, BT2, out, x, pw2b, gamma, 2048, 512, 0, moff);
  }
}

// Round 11
// 187.593 us; speedup vs baseline: 2.0182x; 1.0031x over previous
//
#include <hip/hip_runtime.h>
#include <stdint.h>

// Problem constants
#define BB    16
#define DIMC  512
#define CHC   256
#define REDC  64
#define LL    32          // H == W == 32
#define NTOK  (BB*LL*LL)  // 16384 tokens

typedef unsigned short u16;
typedef unsigned char  u8;
typedef __attribute__((ext_vector_type(4))) float f32x4;

__device__ __forceinline__ float bf2f(u16 u){
  union { unsigned int i; float f; } v; v.i = ((unsigned int)u) << 16; return v.f;
}
__device__ __forceinline__ u16 f2bf(float f){
  union { float f; unsigned int i; } v; v.f = f;
  unsigned int r = (v.i + 0x7FFFu + ((v.i >> 16) & 1u)) >> 16;
  return (u16)r;
}
__device__ __forceinline__ unsigned int pk4_fp8(float a, float b, float c, float d){
  unsigned int w = 0;
  w = __builtin_amdgcn_cvt_pk_fp8_f32(a, b, w, false);
  w = __builtin_amdgcn_cvt_pk_fp8_f32(c, d, w, true);
  return w;
}
__device__ __forceinline__ u8 f2fp8(float f){
  return (u8)(__builtin_amdgcn_cvt_pk_fp8_f32(f, f, 0, false) & 0xffu);
}

// async global->LDS, 16B per lane; LDS base must be wave-uniform.
__device__ __forceinline__ void gload16(const u8* g, u8* l) {
  __builtin_amdgcn_global_load_lds(
      (const __attribute__((address_space(1))) void*)g,
      (__attribute__((address_space(3))) void*)l, 16, 0, 0);
}

// ---------------------------------------------------------------------------
// K0: fused pre-pass. Blocks 0..511: weight transpose fp32 [K][N] -> fp8 [N][K].
// Blocks 512..8703: per-(b,ch) axis means -> g[br][b][c][l].
__global__ __launch_bounds__(256) void k_pre(const float* __restrict__ s1,
    u8* __restrict__ d1, const float* __restrict__ s2, u8* __restrict__ d2,
    const float* __restrict__ x, const float* __restrict__ pe_h,
    const float* __restrict__ pe_w, float* __restrict__ g)
{
  int tid = threadIdx.x;
  if (blockIdx.x < 512) {
    __shared__ float tf[64][65];
    int bid = blockIdx.x;
    const float* src; u8* dst; int K, N, n0, k0;
    if (bid < 256) { src = s1; dst = d1; K = 512;  N = 2048; n0 = (bid & 31) * 64; k0 = (bid >> 5) * 64; }
    else { bid -= 256; src = s2; dst = d2; K = 2048; N = 512; n0 = (bid & 7) * 64; k0 = (bid >> 3) * 64; }
    #pragma unroll
    for (int i = 0; i < 16; ++i) {
      int idx = i*256 + tid; int r = idx >> 6, c = idx & 63;
      tf[r][c] = src[(size_t)(k0 + r) * N + n0 + c];
    }
    __syncthreads();
    // writer: thread -> (c = tid>>2, 16-byte k-group gq = tid&3)
    int c = tid >> 2, gq = tid & 3;
    uint4 o;
    unsigned int* op = (unsigned int*)&o;
    #pragma unroll
    for (int d = 0; d < 4; ++d) {
      int j = gq*16 + d*4;
      op[d] = pk4_fp8(tf[j+0][c], tf[j+1][c], tf[j+2][c], tf[j+3][c]);
    }
    *(uint4*)(dst + (size_t)(n0 + c)*K + k0 + gq*16) = o;
    return;
  }
  // ---- means part ----
  int bc = blockIdx.x - 512;           // b*512 + ch
  int br = (bc & 511) >> 8, c = bc & 255;
  __shared__ float tt[32][33];
  const float* xp = x + (size_t)bc * 1024;
  float4 v = ((const float4*)xp)[tid];
  int h = tid >> 3, w4 = (tid & 7) * 4;
  tt[h][w4+0] = v.x; tt[h][w4+1] = v.y; tt[h][w4+2] = v.z; tt[h][w4+3] = v.w;
  __syncthreads();
  if (tid < 32) {
    float rs = 0.f;
    if (br == 0) {
      #pragma unroll
      for (int w = 0; w < 32; ++w) rs += tt[tid][w];     // mean over W (H-branch)
    } else {
      #pragma unroll
      for (int h2 = 0; h2 < 32; ++h2) rs += tt[h2][tid]; // mean over H (W-branch)
    }
    float tot = rs;
    #pragma unroll
    for (int off = 16; off >= 1; off >>= 1) tot += __shfl_xor(tot, off);
    const float* pe = (br == 0 ? pe_h : pe_w) + c*32;
    float pv = pe[tid];
    float pm = pv;
    #pragma unroll
    for (int off = 16; off >= 1; off >>= 1) pm += __shfl_xor(pm, off);
    int b = bc >> 9;
    float gv = rs * (1.f/32.f) + tot * (1.f/1024.f) + pv + pm * (1.f/32.f);
    g[((size_t)(br*BB + b)*256 + c)*32 + tid] = gv;
  }
}

// ---------------------------------------------------------------------------
// K1a: conv1 partials. grid 128 = (g32 = blk>>2 in [0,32), cq = blk&3).
// Each block: c-range [cq*64, cq*64+64), output partial [blk][64 r][32 l].
__global__ __launch_bounds__(256) void k_gen1(const float* __restrict__ g,
    float* __restrict__ part, const float* __restrict__ g1w_h,
    const float* __restrict__ g1w_w)
{
  int blk = blockIdx.x; int g32 = blk >> 2, cq = blk & 3;
  int br = g32 >> 4;
  const float* g1w = br ? g1w_w : g1w_h;
  __shared__ float gs[64][34];   // padded: col 0 and 33 zero
  int tid = threadIdx.x;
  const float* gb = g + (size_t)g32 * 8192 + cq*64*32;
  if (tid < 64) { gs[tid][0] = 0.f; gs[tid][33] = 0.f; }
  #pragma unroll
  for (int it = 0; it < 8; ++it) {
    int idx = it*256 + tid;
    gs[idx >> 5][1 + (idx & 31)] = gb[idx];
  }
  __syncthreads();
  int r = tid >> 2, l0 = (tid & 3) * 8;
  float acc[8];
  #pragma unroll
  for (int j = 0; j < 8; ++j) acc[j] = 0.f;
  for (int c = 0; c < 64; ++c) {
    const float* wp = g1w + (r*256 + cq*64 + c)*3;
    float w0 = wp[0], w1 = wp[1], w2 = wp[2];
    float gv[10];
    #pragma unroll
    for (int q = 0; q < 10; ++q) gv[q] = gs[c][l0 + q];
    #pragma unroll
    for (int j = 0; j < 8; ++j) acc[j] += w0*gv[j] + w1*gv[j+1] + w2*gv[j+2];
  }
  float* po = part + (size_t)blk*2048 + r*32 + l0;
  #pragma unroll
  for (int j = 0; j < 8; ++j) po[j] = acc[j];
}

// ---------------------------------------------------------------------------
// K1b: reduce partials -> BN -> hardswish -> conv2 -> per-batch norm -> wgt.
// grid 32 = (br*16 + b).
__global__ __launch_bounds__(256) void k_gen2(const float* __restrict__ part,
    float* __restrict__ wout,
    const float* bng_h, const float* bnb_h, const float* bnrm_h, const float* bnrv_h,
    const float* g2w_h, const float* fns_h, const float* fnm_h,
    const float* bng_w, const float* bnb_w, const float* bnrm_w, const float* bnrv_w,
    const float* g2w_w, const float* fns_w, const float* fnm_w)
{
  int g32 = blockIdx.x; int br = g32 >> 4;
  const float* bng  = br ? bng_w  : bng_h;
  const float* bnb  = br ? bnb_w  : bnb_h;
  const float* bnrm = br ? bnrm_w : bnrm_h;
  const float* bnrv = br ? bnrv_w : bnrv_h;
  const float* g2w  = br ? g2w_w  : g2w_h;
  const float* fns  = br ? fns_w  : fns_h;
  const float* fnm  = br ? fnm_w  : fnm_h;

  __shared__ float h1[64][34];
  __shared__ float red[8];
  int tid = threadIdx.x;
  if (tid < 64) { h1[tid][0] = 0.f; h1[tid][33] = 0.f; }
  {
    int r = tid >> 2, l0 = (tid & 3) * 8;
    const float* p0 = part + (size_t)(g32*4 + 0)*2048 + r*32 + l0;
    const float* p1 = part + (size_t)(g32*4 + 1)*2048 + r*32 + l0;
    const float* p2 = part + (size_t)(g32*4 + 2)*2048 + r*32 + l0;
    const float* p3 = part + (size_t)(g32*4 + 3)*2048 + r*32 + l0;
    float sc = bng[r] * rsqrtf(bnrv[r] + 1e-5f);
    float sh = bnb[r] - bnrm[r] * sc;
    #pragma unroll
    for (int j = 0; j < 8; ++j) {
      float v2 = (p0[j] + p1[j] + p2[j] + p3[j])*sc + sh;            // BN
      float hs = v2 * fminf(fmaxf(v2 + 3.f, 0.f), 6.f) * (1.f/6.f);  // hardswish
      h1[r][1 + l0 + j] = hs;
    }
  }
  __syncthreads();

  // conv2: thread -> one output channel c, all 32 l
  int c = tid;
  float a2[32];
  #pragma unroll
  for (int l = 0; l < 32; ++l) a2[l] = 0.f;
  for (int r = 0; r < 64; ++r) {
    const float* wp = g2w + (c*64 + r)*3;
    float w0 = wp[0], w1 = wp[1], w2 = wp[2];
    float hv[34];
    #pragma unroll
    for (int q = 0; q < 34; ++q) hv[q] = h1[r][q];
    #pragma unroll
    for (int l = 0; l < 32; ++l) a2[l] += w0*hv[l] + w1*hv[l+1] + w2*hv[l+2];
  }
  // per-batch mean/var over all (c,l)
  float s = 0.f, sq = 0.f;
  #pragma unroll
  for (int l = 0; l < 32; ++l) { s += a2[l]; sq += a2[l]*a2[l]; }
  #pragma unroll
  for (int off = 32; off >= 1; off >>= 1) { s += __shfl_xor(s, off); sq += __shfl_xor(sq, off); }
  int wid = tid >> 6;
  if ((tid & 63) == 0) { red[wid*2] = s; red[wid*2+1] = sq; }
  __syncthreads();
  float S  = red[0] + red[2] + red[4] + red[6];
  float SQ = red[1] + red[3] + red[5] + red[7];
  float u   = S * (1.f/8192.f);
  float var = SQ * (1.f/8192.f) - u*u;
  float inv = rsqrtf(var + 1e-6f);
  float* wo = wout + (size_t)g32*8192 + c*32;
  #pragma unroll
  for (int l = 0; l < 32; ++l)
    wo[l] = (a2[l] - u)*inv*fns[c*32 + l] + fnm[c*32 + l];
}

// ---------------------------------------------------------------------------
// K3: circulant apply per (b,ch). Writes ybr bf16 in (b,ch,h,w) layout.
__global__ __launch_bounds__(256) void k_circ(const float* __restrict__ x,
    const float* __restrict__ pe_h, const float* __restrict__ pe_w,
    const float* __restrict__ bias_h, const float* __restrict__ bias_w,
    const float* __restrict__ wgt, u16* __restrict__ ybr)
{
  int bc = blockIdx.x;
  int b = bc >> 9, ch = bc & 511, br = ch >> 8, c = ch & 255;
  __shared__ float xs[32][33];
  __shared__ float ww[32];
  int tid = threadIdx.x;
  const float* xp = x + (size_t)bc * 1024;
  float4 v = ((const float4*)xp)[tid];
  int h = tid >> 3, w4 = (tid & 7) * 4;
  if (br == 0) {
    float p = pe_h[c*32 + h];
    xs[h][w4+0] = v.x + p; xs[h][w4+1] = v.y + p;
    xs[h][w4+2] = v.z + p; xs[h][w4+3] = v.w + p;
  } else {
    xs[h][w4+0] = v.x + pe_w[c*32 + w4+0];
    xs[h][w4+1] = v.y + pe_w[c*32 + w4+1];
    xs[h][w4+2] = v.z + pe_w[c*32 + w4+2];
    xs[h][w4+3] = v.w + pe_w[c*32 + w4+3];
  }
  if (tid < 32) ww[tid] = wgt[((size_t)(br*BB + b)*256 + c)*32 + tid];
  __syncthreads();
  float bias = (br ? bias_w : bias_h)[c];
  int i = tid >> 3;
  float o0 = bias, o1 = bias, o2 = bias, o3 = bias;
  if (br == 0) {
    #pragma unroll
    for (int k = 0; k < 32; ++k) {
      float wk = ww[k]; int rr = (i + k) & 31;
      o0 += wk*xs[rr][w4+0]; o1 += wk*xs[rr][w4+1];
      o2 += wk*xs[rr][w4+2]; o3 += wk*xs[rr][w4+3];
    }
  } else {
    #pragma unroll
    for (int k = 0; k < 32; ++k) {
      float wk = ww[k];
      o0 += wk*xs[i][(w4+0+k) & 31]; o1 += wk*xs[i][(w4+1+k) & 31];
      o2 += wk*xs[i][(w4+2+k) & 31]; o3 += wk*xs[i][(w4+3+k) & 31];
    }
  }
  ushort4 o; o.x = f2bf(o0); o.y = f2bf(o1); o.z = f2bf(o2); o.w = f2bf(o3);
  ((ushort4*)(ybr + (size_t)bc * 1024))[tid] = o;
}

// ---------------------------------------------------------------------------
// K4: transpose (b,ch,h,w)->token-major + LayerNorm + fp8 pack. A8 [token][512].
__global__ __launch_bounds__(256) void k_ln(const u16* __restrict__ ybr,
    const float* __restrict__ ln_w, const float* __restrict__ ln_b,
    u8* __restrict__ A8)
{
  int bh = blockIdx.x; int b = bh >> 5, h = bh & 31;
  __shared__ float ys[512][33];
  __shared__ float ps[8][32], pq[8][32];
  __shared__ float mus[32], rstds[32];
  __shared__ float lw[512], lb[512];
  int tid = threadIdx.x;
  lw[tid]       = ln_w[tid];       lb[tid]       = ln_b[tid];
  lw[tid + 256] = ln_w[tid + 256]; lb[tid + 256] = ln_b[tid + 256];
  #pragma unroll
  for (int it = 0; it < 16; ++it) {
    int vid = it*256 + tid; int ch = vid >> 3; int w4 = (vid & 7) * 4;
    ushort4 v = *(const ushort4*)(ybr + (size_t)(b*512 + ch)*1024 + h*32 + w4);
    ys[ch][w4+0] = bf2f(v.x); ys[ch][w4+1] = bf2f(v.y);
    ys[ch][w4+2] = bf2f(v.z); ys[ch][w4+3] = bf2f(v.w);
  }
  __syncthreads();
  int w = tid & 31, gq = tid >> 5;
  float s = 0.f, sq = 0.f;
  for (int cc = gq*64; cc < gq*64 + 64; ++cc) { float vv = ys[cc][w]; s += vv; sq += vv*vv; }
  ps[gq][w] = s; pq[gq][w] = sq;
  __syncthreads();
  if (tid < 32) {
    float S = 0.f, SQ = 0.f;
    #pragma unroll
    for (int q = 0; q < 8; ++q) { S += ps[q][tid]; SQ += pq[q][tid]; }
    float mu = S * (1.f/512.f);
    float var = SQ * (1.f/512.f) - mu*mu;
    mus[tid] = mu; rstds[tid] = rsqrtf(var + 1e-6f);
  }
  __syncthreads();
  u8* Arow = A8 + (size_t)(b*1024 + h*32) * 512;
  #pragma unroll
  for (int it = 0; it < 16; ++it) {
    int idx = it*256 + tid;                 // 4096 dword groups
    int w2 = idx >> 7, cg = idx & 127; int cc = cg*4;
    float mu = mus[w2], rs2 = rstds[w2];
    float v0 = (ys[cc+0][w2] - mu) * rs2 * lw[cc+0] + lb[cc+0];
    float v1 = (ys[cc+1][w2] - mu) * rs2 * lw[cc+1] + lb[cc+1];
    float v2 = (ys[cc+2][w2] - mu) * rs2 * lw[cc+2] + lb[cc+2];
    float v3 = (ys[cc+3][w2] - mu) * rs2 * lw[cc+3] + lb[cc+3];
    ((unsigned int*)(Arow + (size_t)w2*512))[cg] = pk4_fp8(v0, v1, v2, v3);
  }
}

// ---------------------------------------------------------------------------
// K5/K6: fp8 MFMA GEMM, 128x128 tile, BK=64, 8 waves / 512 threads,
// mfma_f32_16x16x32_fp8_fp8. DEPTH-2 prefetch with 3 LDS slots (48 KB total,
// fp8 makes this fit at 3 blocks/CU — R6's bf16 3-slot was 96 KB -> 1 block).
// Iter t: stage(t+2 -> slot (t-1)%3); vmcnt(4) [= tiles t+1,t+2 in flight,
// tile t confirmed, TWO iterations of latency cover]; barrier; read+MFMA;
// barrier. Tail: vmcnt(2) -> vmcnt(0). Race-free: staged slot's last reads
// completed before iter (t-1)'s closing barrier.
// Swizzle: 16B chunk c of 64B row r stored at c ^ ((r>>1)&3) (involution on
// BOTH global source and read addr).
// EPI=1: Z = fp8(gelu_approx(A@B + bias)). EPI=2: residual fp32 out.
template<int EPI>
__global__ __launch_bounds__(512, 6) void k_gemm(
    const u8* __restrict__ A, const u8* __restrict__ BT,
    void* __restrict__ outv, const float* __restrict__ xin,
    const float* __restrict__ bias, const float* __restrict__ gamma,
    int K, int N, int a_row_off, int out_row_off)
{
  __shared__ u8 As[3][8192];
  __shared__ u8 Bs[3][8192];
  int tid = threadIdx.x;
  int m0 = blockIdx.x * 128, n0 = blockIdx.y * 128;
  int lane = tid & 63, wid = tid >> 6;
  int wr = wid >> 1, wc = wid & 1;          // wave tile: rows wr*32.., cols wc*64..
  f32x4 acc[2][4];
  #pragma unroll
  for (int mi = 0; mi < 2; ++mi)
    #pragma unroll
    for (int ni = 0; ni < 4; ++ni) acc[mi][ni] = (f32x4){0.f,0.f,0.f,0.f};

  // staging: tile = 128 rows x 64 B; unit (=wave) u covers rows 16u..16u+15.
  // lane l -> row 16u + (l>>2), 16B chunk (l&3); source chunk XOR-swizzled.
  int rloc = (wid << 4) + (lane >> 2);
  int cp   = (lane & 3) ^ ((lane >> 3) & 3);
  const u8* aSrc = A  + (size_t)(a_row_off + m0 + rloc)*K + cp*16;
  const u8* bSrc = BT + (size_t)(n0 + rloc)*K + cp*16;
  int ldsOff = wid * 1024;                  // wave-uniform byte base

  auto stage = [&](int t, int slot) {
    int k0 = t << 6;
    gload16(aSrc + k0, &As[slot][ldsOff]);
    gload16(bSrc + k0, &Bs[slot][ldsOff]);
  };
  // b64 fragment read: global bytes [row][kk + q*8 .. +8]
  auto lds8 = [&](const u8* base, int row, int kk, int q) -> long {
    int j = (kk >> 4) + (q >> 1);
    int byte = row*64 + ((j ^ ((row >> 1) & 3)) << 4) + ((q & 1) << 3);
    return *(const long*)(base + byte);
  };

  int nt = K >> 6;
  stage(0, 0);                              // prologue: depth-2
  stage(1, 1);

  int sr = 0;                               // slot of tile t
  for (int t = 0; t < nt; ++t) {
    if (t + 2 < nt) {
      int sw = (sr == 0) ? 2 : sr - 1;      // (t+2)%3 == (t-1)%3
      stage(t + 2, sw);
      asm volatile("s_waitcnt vmcnt(4)" ::: "memory");   // tile t landed; t+1,t+2 in flight
    } else if (t + 1 < nt) {
      asm volatile("s_waitcnt vmcnt(2)" ::: "memory");   // tile t landed; t+1 in flight
    } else {
      asm volatile("s_waitcnt vmcnt(0)" ::: "memory");
    }
    __builtin_amdgcn_s_barrier();                        // tile t collectively valid
    const u8* Ar = &As[sr][0];
    const u8* Br = &Bs[sr][0];
    int q = lane >> 4;
    #pragma unroll
    for (int kk = 0; kk < 64; kk += 32) {
      long af[2], bfr[4];
      #pragma unroll
      for (int mi = 0; mi < 2; ++mi)
        af[mi] = lds8(Ar, wr*32 + mi*16 + (lane & 15), kk, q);
      #pragma unroll
      for (int ni = 0; ni < 4; ++ni)
        bfr[ni] = lds8(Br, wc*64 + ni*16 + (lane & 15), kk, q);
      #pragma unroll
      for (int mi = 0; mi < 2; ++mi)
        #pragma unroll
        for (int ni = 0; ni < 4; ++ni)
          acc[mi][ni] = __builtin_amdgcn_mfma_f32_16x16x32_fp8_fp8(af[mi], bfr[ni], acc[mi][ni], 0, 0, 0);
    }
    __builtin_amdgcn_s_barrier();   // protect the slot the next stage overwrites
    sr = (sr == 2) ? 0 : sr + 1;
  }

  // epilogue: D layout col = lane&15, row = (lane>>4)*4 + reg
  #pragma unroll
  for (int mi = 0; mi < 2; ++mi) {
    #pragma unroll
    for (int ni = 0; ni < 4; ++ni) {
      int n = n0 + wc*64 + ni*16 + (lane & 15);
      float bn = bias[n];
      #pragma unroll
      for (int r = 0; r < 4; ++r) {
        int m = m0 + wr*32 + mi*16 + (lane >> 4)*4 + r;
        float v = acc[mi][ni][r] + bn;
        if (EPI == 1) {
          float ge = v / (1.f + __expf(-1.702f * v));   // sigmoid-approx GELU
          ((u8*)outv)[(size_t)m*N + n] = f2fp8(ge);
        } else {
          float yv = gamma[n] * v;
          int mg = out_row_off + m;
          int bb = mg >> 10, hh = (mg >> 5) & 31, wv = mg & 31;
          size_t oi = ((size_t)(bb*512 + n))*1024 + hh*32 + wv;
          ((float*)outv)[oi] = xin[oi] + yv;
        }
      }
    }
  }
}

// ---------------------------------------------------------------------------
extern "C" void kernel_launch(void* const* d_in, const int* in_sizes, int n_in,
                              void* d_out, int out_size, void* d_ws, size_t ws_size,
                              hipStream_t stream)
{
  const float* x      = (const float*)d_in[0];
  const float* pe_h   = (const float*)d_in[1];
  const float* g1w_h  = (const float*)d_in[2];
  const float* bng_h  = (const float*)d_in[3];
  const float* bnb_h  = (const float*)d_in[4];
  const float* bnrm_h = (const float*)d_in[5];
  const float* bnrv_h = (const float*)d_in[6];
  const float* g2w_h  = (const float*)d_in[7];
  const float* fns_h  = (const float*)d_in[8];
  const float* fnm_h  = (const float*)d_in[9];
  const float* bias_h = (const float*)d_in[10];
  const float* pe_w   = (const float*)d_in[11];
  const float* g1w_w  = (const float*)d_in[12];
  const float* bng_w  = (const float*)d_in[13];
  const float* bnb_w  = (const float*)d_in[14];
  const float* bnrm_w = (const float*)d_in[15];
  const float* bnrv_w = (const float*)d_in[16];
  const float* g2w_w  = (const float*)d_in[17];
  const float* fns_w  = (const float*)d_in[18];
  const float* fnm_w  = (const float*)d_in[19];
  const float* bias_w = (const float*)d_in[20];
  const float* ln_w   = (const float*)d_in[21];
  const float* ln_b   = (const float*)d_in[22];
  const float* pw1w   = (const float*)d_in[23];
  const float* pw1b   = (const float*)d_in[24];
  const float* pw2w   = (const float*)d_in[25];
  const float* pw2b   = (const float*)d_in[26];
  const float* gamma  = (const float*)d_in[27];
  float* out = (float*)d_out;

  char* ws = (char*)d_ws;
  size_t off = 0;
  auto carve = [&](size_t bytes) -> void* {
    void* p = ws + off; off += (bytes + 255) & ~(size_t)255; return p;
  };
  float* g    = (float*)carve((size_t)2*BB*256*32*4);   // 1 MB
  float* wgt  = (float*)carve((size_t)2*BB*256*32*4);   // 1 MB
  float* part = (float*)carve((size_t)128*2048*4);      // 1 MB conv1 partials
  u8* BT1     = (u8*)carve((size_t)2048*512);           // 1 MB fp8
  u8* BT2     = (u8*)carve((size_t)512*2048);           // 1 MB fp8
  u8* Abuf    = (u8*)carve((size_t)NTOK*512);           // 8.4 MB fp8
  size_t tail = off;                                    // ybr / Z share this region
  u16* ybr = (u16*)(ws + tail);
  u8*  Z   = (u8*)(ws + tail);                          // Z overwrites dead ybr
  size_t ybr_bytes = (size_t)NTOK*512*2;                // 16.8 MB
  int nch = 1;                                          // chunk M so Z fits in ws
  while (nch < 16) {
    size_t zb = ((size_t)NTOK/nch)*2048;                // fp8 Z
    size_t need = tail + (zb > ybr_bytes ? zb : ybr_bytes);
    if (need <= ws_size) break;
    nch *= 2;
  }

  k_pre<<<512 + BB*512, 256, 0, stream>>>(pw1w, BT1, pw2w, BT2, x, pe_h, pe_w, g);
  k_gen1<<<128, 256, 0, stream>>>(g, part, g1w_h, g1w_w);
  k_gen2<<<32, 256, 0, stream>>>(part, wgt,
      bng_h, bnb_h, bnrm_h, bnrv_h, g2w_h, fns_h, fnm_h,
      bng_w, bnb_w, bnrm_w, bnrv_w, g2w_w, fns_w, fnm_w);
  k_circ<<<BB*512, 256, 0, stream>>>(x, pe_h, pe_w, bias_h, bias_w, wgt, ybr);
  k_ln<<<BB*LL, 256, 0, stream>>>(ybr, ln_w, ln_b, Abuf);

  int Mc = NTOK / nch;
  for (int ci = 0; ci < nch; ++ci) {
    int moff = ci * Mc;
    k_gemm<1><<<dim3(Mc/128, 2048/128), 512, 0, stream>>>(
        Abuf, BT1, Z, nullptr, pw1b, nullptr, 512, 2048, moff, 0);
    k_gemm<2><<<dim3(Mc/128, 512/128), 512, 0, stream>>>(
        Z, BT2, out, x, pw2b, gamma, 2048, 512, 0, moff);
  }
}